// Round 14
// baseline (81.235 us; speedup 1.0000x reference)
//
#include <hip/hip_runtime.h>
#include <math.h>

typedef __attribute__((ext_vector_type(8))) short bf16x8;
typedef __attribute__((ext_vector_type(4))) float f32x4;

#define NK   2048
#define KT   16        // k per block tile
#define NTHR 512

// ws layout: mRb bf16[1M] @0 (2MB), mIb @2MB (2MB), part f32[512*1024] @4MB (2MB)
#define MULTI_ELEMS (1 << 20)
#define PART_OFF    (4u << 20)

__device__ __forceinline__ unsigned short f2bf(float f) {
    union { float f; unsigned u; } v; v.f = f;
    const unsigned r = (v.u + 0x7fffu + ((v.u >> 16) & 1u)) >> 16;  // RNE
    return (unsigned short)r;
}

// ---------------------------------------------------------------------------
// Kernel 1: multi = image*csm -> bf16 planes in ws. (proven R12/R13)
// ---------------------------------------------------------------------------
__global__ __launch_bounds__(256)
void make_multi_bf16(const float* __restrict__ imr, const float* __restrict__ imi,
                     const float* __restrict__ csr, const float* __restrict__ csi,
                     unsigned short* __restrict__ mRb, unsigned short* __restrict__ mIb)
{
    const int gid = blockIdx.x * 256 + threadIdx.x;   // [0, 262144)
    const int p   = gid * 4;                          // flat [t][n][y][x]
    const int x   = p & 127;
    const int y   = (p >> 7) & 127;
    const int n   = (p >> 14) & 31;
    const int t   = p >> 19;
    const int d   = n & 3;
    const int ch  = n >> 2;
    const int io  = ((t * 4 + d) * 128 + y) * 128 + x;
    const int co  = (((t * 8 + ch) * 4 + d) * 128 + y) * 128 + x;

    const float4 ar = *(const float4*)(imr + io);
    const float4 ai = *(const float4*)(imi + io);
    const float4 br = *(const float4*)(csr + co);
    const float4 bi = *(const float4*)(csi + co);

    ushort4 sr, si;
    sr.x = f2bf(ar.x*br.x - ai.x*bi.x);  si.x = f2bf(ar.x*bi.x + ai.x*br.x);
    sr.y = f2bf(ar.y*br.y - ai.y*bi.y);  si.y = f2bf(ar.y*bi.y + ai.y*br.y);
    sr.z = f2bf(ar.z*br.z - ai.z*bi.z);  si.z = f2bf(ar.z*bi.z + ai.z*br.z);
    sr.w = f2bf(ar.w*br.w - ai.w*bi.w);  si.w = f2bf(ar.w*bi.w + ai.w*br.w);
    *(ushort4*)(mRb + p) = sr;
    *(ushort4*)(mIb + p) = si;
}

// ---------------------------------------------------------------------------
// Kernel 2: separable MFMA NUDFT.
// C[n,k] = sum_y Ey[k,y] * (sum_x M[n,y,x] * Ex[k,x])
// Grid 512 = 2t x 128 ktiles x 2 y-halves; 8 waves x 8 y each.
// B (=Ex) frags are y-invariant: built once per block from sincos, kept in
// 12 bf16x8 regs. Per y: 16 A-loads + 32 mfma into zeroed R_y, then per-lane
// complex Ey scale into persistent C accumulators (Ey depends only on
// k = lane&15). Lane mappings identical to R13 (HW-verified).
// ---------------------------------------------------------------------------
__global__ __launch_bounds__(NTHR, 2)
void nufft_mfma2(const float* __restrict__ traj,
                 const unsigned short* __restrict__ mRb,
                 const unsigned short* __restrict__ mIb,
                 float* __restrict__ part)
{
    __shared__ float red[4][1024];        // cross-wave C reduction (16 KB)

    const int b   = blockIdx.x;
    const int xcd = b & 7;                // XCD swizzle: 0-3 -> t=0, 4-7 -> t=1
    const int t   = xcd >> 2;
    const int idx = (xcd & 3) * 64 + (b >> 3);   // bijective [0,256)
    const int kt  = idx >> 1;
    const int ph  = idx & 1;              // y-half
    const int k0  = kt * KT;

    const int wv = threadIdx.x >> 6;
    const int l  = threadIdx.x & 63;
    const int kl = l & 15;                // A: row n; B: col k; C: col k
    const int g  = l >> 4;                // k-slice group

    const float ky = traj[(t * 2 + 0) * NK + k0 + kl];
    const float kx = traj[(t * 2 + 1) * NK + k0 + kl];

    // ---- B frags: Ex[k0+kl][x], x = g*8 + ks*32 + j  (y-invariant) ----
    bf16x8 bEr[4], bEiN[4], bEi[4];
#pragma unroll
    for (int ks = 0; ks < 4; ++ks) {
#pragma unroll
        for (int j = 0; j < 8; ++j) {
            const int x = g * 8 + ks * 32 + j;
            float s, c;
            sincosf(-kx * (float)(x - 64), &s, &c);   // exp(-i*kx*(x-64))
            bEr[ks][j]  = (short)f2bf(c);
            bEiN[ks][j] = (short)f2bf(-s);
            bEi[ks][j]  = (short)(bEiN[ks][j] ^ (short)0x8000);
        }
    }

    // ---- Ey per lane for this wave's 8 y values ----
    const int y0 = ph * 64 + wv * 8;
    float2 eyv[8];
#pragma unroll
    for (int yi = 0; yi < 8; ++yi) {
        float s, c;
        sincosf(-ky * (float)(y0 + yi - 64), &s, &c); // exp(-i*ky*(y-64))
        eyv[yi] = make_float2(c, s);
    }

    const unsigned short* pAr = mRb + (((size_t)t * 32) << 14);
    const unsigned short* pAi = mIb + (((size_t)t * 32) << 14);

    f32x4 cR0 = {0.f,0.f,0.f,0.f}, cI0 = {0.f,0.f,0.f,0.f};
    f32x4 cR1 = {0.f,0.f,0.f,0.f}, cI1 = {0.f,0.f,0.f,0.f};

    for (int yi = 0; yi < 8; ++yi) {
        const int y    = y0 + yi;
        const int xoff = y * 128 + g * 8;      // p = y*128 + x

        f32x4 rR0 = {0.f,0.f,0.f,0.f}, rI0 = {0.f,0.f,0.f,0.f};
        f32x4 rR1 = {0.f,0.f,0.f,0.f}, rI1 = {0.f,0.f,0.f,0.f};

#pragma unroll
        for (int ks = 0; ks < 4; ++ks) {
            const int pa = xoff + ks * 32;
            const bf16x8 aR0 = *(const bf16x8*)(pAr + (((size_t)kl)      << 14) + pa);
            const bf16x8 aI0 = *(const bf16x8*)(pAi + (((size_t)kl)      << 14) + pa);
            const bf16x8 aR1 = *(const bf16x8*)(pAr + (((size_t)kl + 16) << 14) + pa);
            const bf16x8 aI1 = *(const bf16x8*)(pAi + (((size_t)kl + 16) << 14) + pa);

            rR0 = __builtin_amdgcn_mfma_f32_16x16x32_bf16(aR0, bEr[ks],  rR0, 0, 0, 0);
            rR0 = __builtin_amdgcn_mfma_f32_16x16x32_bf16(aI0, bEiN[ks], rR0, 0, 0, 0);
            rI0 = __builtin_amdgcn_mfma_f32_16x16x32_bf16(aR0, bEi[ks],  rI0, 0, 0, 0);
            rI0 = __builtin_amdgcn_mfma_f32_16x16x32_bf16(aI0, bEr[ks],  rI0, 0, 0, 0);
            rR1 = __builtin_amdgcn_mfma_f32_16x16x32_bf16(aR1, bEr[ks],  rR1, 0, 0, 0);
            rR1 = __builtin_amdgcn_mfma_f32_16x16x32_bf16(aI1, bEiN[ks], rR1, 0, 0, 0);
            rI1 = __builtin_amdgcn_mfma_f32_16x16x32_bf16(aR1, bEi[ks],  rI1, 0, 0, 0);
            rI1 = __builtin_amdgcn_mfma_f32_16x16x32_bf16(aI1, bEr[ks],  rI1, 0, 0, 0);
        }

        // C += Ey * R_y  (per-lane complex scalar: Ey depends only on k=kl)
        const float2 e = eyv[yi];
#pragma unroll
        for (int r = 0; r < 4; ++r) {
            cR0[r] += e.x * rR0[r] - e.y * rI0[r];
            cI0[r] += e.x * rI0[r] + e.y * rR0[r];
            cR1[r] += e.x * rR1[r] - e.y * rI1[r];
            cI1[r] += e.x * rI1[r] + e.y * rR1[r];
        }
    }

    // ---- cross-wave reduction (layout identical to R13) ----
    const int slot = wv & 3;
    if (wv < 4) {
#pragma unroll
        for (int r = 0; r < 4; ++r) {
            const int n0  = g * 4 + r;
            const int i00 = (n0 * 16 + kl) * 2;
            const int i10 = ((n0 + 16) * 16 + kl) * 2;
            red[slot][i00]     = cR0[r];
            red[slot][i00 + 1] = cI0[r];
            red[slot][i10]     = cR1[r];
            red[slot][i10 + 1] = cI1[r];
        }
    }
    __syncthreads();
    if (wv >= 4) {
#pragma unroll
        for (int r = 0; r < 4; ++r) {
            const int n0  = g * 4 + r;
            const int i00 = (n0 * 16 + kl) * 2;
            const int i10 = ((n0 + 16) * 16 + kl) * 2;
            red[slot][i00]     += cR0[r];
            red[slot][i00 + 1] += cI0[r];
            red[slot][i10]     += cR1[r];
            red[slot][i10 + 1] += cI1[r];
        }
    }
    __syncthreads();

    {
        const int bp = ((t * 128 + kt) * 2 + ph) * 1024;
        for (int f = threadIdx.x; f < 1024; f += NTHR)
            part[bp + f] = red[0][f] + red[1][f] + red[2][f] + red[3][f];
    }
}

// ---------------------------------------------------------------------------
// Kernel 3: sum the two y-half partials, write f32 planar output. (proven)
// ---------------------------------------------------------------------------
__global__ __launch_bounds__(256)
void reduce_out(const float* __restrict__ part, float* __restrict__ out)
{
    const int gidx = blockIdx.x * 256 + threadIdx.x;  // [0, 131072)
    const int t  = gidx >> 16;
    const int r1 = gidx & 65535;
    const int kt = r1 >> 9;
    const int r2 = r1 & 511;
    const int n  = r2 >> 4;
    const int kl = r2 & 15;

    const int bp = ((t * 128 + kt) * 2) * 1024;
    const int fr = (n * 16 + kl) * 2;
    const float re = part[bp + fr]     + part[bp + 1024 + fr];
    const float im = part[bp + fr + 1] + part[bp + 1024 + fr + 1];

    const int oi = (t * 32 + n) * 2048 + kt * KT + kl;
    out[oi]           = re;    // real plane
    out[131072 + oi]  = im;    // imag plane
}

extern "C" void kernel_launch(void* const* d_in, const int* in_sizes, int n_in,
                              void* d_out, int out_size, void* d_ws, size_t ws_size,
                              hipStream_t stream) {
    const float* imr  = (const float*)d_in[0];   // image_real (dict order)
    const float* imi  = (const float*)d_in[1];   // image_imag
    const float* csr  = (const float*)d_in[2];   // csm_real
    const float* csi  = (const float*)d_in[3];   // csm_imag
    const float* traj = (const float*)d_in[4];   // traj
    float* out = (float*)d_out;

    unsigned short* mRb = (unsigned short*)d_ws;
    unsigned short* mIb = mRb + MULTI_ELEMS;
    float* part = (float*)((char*)d_ws + PART_OFF);

    make_multi_bf16<<<dim3(1024), dim3(256), 0, stream>>>(imr, imi, csr, csi, mRb, mIb);
    nufft_mfma2<<<dim3(512), dim3(NTHR), 0, stream>>>(traj, mRb, mIb, part);
    reduce_out<<<dim3(512), dim3(256), 0, stream>>>(part, out);
}

// Round 17
// 74.839 us; speedup vs baseline: 1.0855x; 1.0855x over previous
//
#include <hip/hip_runtime.h>
#include <math.h>

typedef __attribute__((ext_vector_type(8))) short bf16x8;
typedef __attribute__((ext_vector_type(4))) float f32x4;

#define NK   2048
#define KT   16
#define NTHR 256   // 4 waves

// ws: mRb bf16[1M] @0 (2MB), mIb @2MB (2MB), part f32[1024*1024] @4MB (4MB)
#define MULTI_ELEMS (1 << 20)
#define PART_OFF    (4u << 20)

__device__ __forceinline__ unsigned short f2bf(float f) {
    union { float f; unsigned u; } v; v.f = f;
    const unsigned r = (v.u + 0x7fffu + ((v.u >> 16) & 1u)) >> 16;  // RNE
    return (unsigned short)r;
}

// ---------------------------------------------------------------------------
// Kernel 1: multi = image*csm -> bf16 planes (proven R12-R14)
// ---------------------------------------------------------------------------
__global__ __launch_bounds__(256)
void make_multi_bf16(const float* __restrict__ imr, const float* __restrict__ imi,
                     const float* __restrict__ csr, const float* __restrict__ csi,
                     unsigned short* __restrict__ mRb, unsigned short* __restrict__ mIb)
{
    const int gid = blockIdx.x * 256 + threadIdx.x;
    const int p   = gid * 4;
    const int x   = p & 127;
    const int y   = (p >> 7) & 127;
    const int n   = (p >> 14) & 31;
    const int t   = p >> 19;
    const int d   = n & 3;
    const int ch  = n >> 2;
    const int io  = ((t * 4 + d) * 128 + y) * 128 + x;
    const int co  = (((t * 8 + ch) * 4 + d) * 128 + y) * 128 + x;

    const float4 ar = *(const float4*)(imr + io);
    const float4 ai = *(const float4*)(imi + io);
    const float4 br = *(const float4*)(csr + co);
    const float4 bi = *(const float4*)(csi + co);

    ushort4 sr, si;
    sr.x = f2bf(ar.x*br.x - ai.x*bi.x);  si.x = f2bf(ar.x*bi.x + ai.x*br.x);
    sr.y = f2bf(ar.y*br.y - ai.y*bi.y);  si.y = f2bf(ar.y*bi.y + ai.y*br.y);
    sr.z = f2bf(ar.z*br.z - ai.z*bi.z);  si.z = f2bf(ar.z*bi.z + ai.z*br.z);
    sr.w = f2bf(ar.w*br.w - ai.w*bi.w);  si.w = f2bf(ar.w*bi.w + ai.w*br.w);
    *(ushort4*)(mRb + p) = sr;
    *(ushort4*)(mIb + p) = si;
}

// ---------------------------------------------------------------------------
// Kernel 2: R14's inline body (proven) + R13's tab (proven), 4-wave blocks,
// grid 1024 = 2t x 128kt x 4 y-quarters -> 4 blocks/CU for TLP latency hiding.
// NO register-array prefetch (R15/R16's failing skeleton banned).
// Lane maps (HW-proven R13/R14): A row=kl(/+16), k-slice g=l>>4; B col=kl;
// C row m=g*4+r, col=kl.
// ---------------------------------------------------------------------------
__global__ __launch_bounds__(NTHR, 4)
void nufft_mfma5(const float* __restrict__ traj,
                 const unsigned short* __restrict__ mRb,
                 const unsigned short* __restrict__ mIb,
                 float* __restrict__ part)
{
    __shared__ float2 tab[2][128][16];   // [0]=Ey[y][kl], [1]=Ex[x][kl] (32 KB)
    __shared__ float  red[2][1024];      // cross-wave reduction (8 KB)

    const int b   = blockIdx.x;          // [0, 1024)
    const int xcd = b & 7;               // XCD swizzle: 0-3 -> t=0, 4-7 -> t=1
    const int t   = xcd >> 2;
    const int idx = (xcd & 3) * 128 + (b >> 3);  // bijective [0,512)
    const int kt  = idx >> 2;
    const int yq  = idx & 3;             // y-quarter
    const int k0  = kt * KT;

    // ---- tables: exp(-i * kv * (c-64)); 16 sincos per thread (R13 verbatim)
    for (int i = threadIdx.x; i < 2 * 128 * KT; i += NTHR) {
        const int ax  = i >> 11;         // 0=y (ky), 1=x (kx)
        const int rem = i & 2047;
        const int c   = rem >> 4;
        const int kli = rem & 15;
        const float kv = traj[(t * 2 + ax) * NK + k0 + kli];
        float s, co;
        sincosf(-kv * (float)(c - 64), &s, &co);
        tab[ax][c][kli] = make_float2(co, s);
    }
    __syncthreads();

    const int wv = threadIdx.x >> 6;     // 0..3
    const int l  = threadIdx.x & 63;
    const int kl = l & 15;
    const int g  = l >> 4;

    // ---- B frags from tab (y-invariant): Ex[k0+kl][x], x = ks*32 + g*8 + j
    bf16x8 bEr[4], bEiN[4];
#pragma unroll
    for (int ks = 0; ks < 4; ++ks) {
#pragma unroll
        for (int j = 0; j < 8; ++j) {
            const float2 ex = tab[1][ks * 32 + g * 8 + j][kl];
            bEr[ks][j]  = (short)f2bf(ex.x);
            bEiN[ks][j] = (short)f2bf(-ex.y);
        }
    }

    const unsigned short* pAr = mRb + (((size_t)t * 32) << 14);
    const unsigned short* pAi = mIb + (((size_t)t * 32) << 14);
    const int y0 = yq * 32 + wv * 8;

    f32x4 cR0 = {0.f,0.f,0.f,0.f}, cI0 = {0.f,0.f,0.f,0.f};
    f32x4 cR1 = {0.f,0.f,0.f,0.f}, cI1 = {0.f,0.f,0.f,0.f};

    for (int yi = 0; yi < 8; ++yi) {
        const int y    = y0 + yi;
        const int xoff = y * 128 + g * 8;

        f32x4 rR0 = {0.f,0.f,0.f,0.f}, rI0 = {0.f,0.f,0.f,0.f};
        f32x4 rR1 = {0.f,0.f,0.f,0.f}, rI1 = {0.f,0.f,0.f,0.f};

#pragma unroll
        for (int ks = 0; ks < 4; ++ks) {
            const int pa = xoff + ks * 32;
            const bf16x8 aR0 = *(const bf16x8*)(pAr + (((size_t)kl)      << 14) + pa);
            const bf16x8 aI0 = *(const bf16x8*)(pAi + (((size_t)kl)      << 14) + pa);
            const bf16x8 aR1 = *(const bf16x8*)(pAr + (((size_t)kl + 16) << 14) + pa);
            const bf16x8 aI1 = *(const bf16x8*)(pAi + (((size_t)kl + 16) << 14) + pa);

            bf16x8 bEi_;
#pragma unroll
            for (int j = 0; j < 8; ++j) bEi_[j] = (short)(bEiN[ks][j] ^ (short)0x8000);

            rR0 = __builtin_amdgcn_mfma_f32_16x16x32_bf16(aR0, bEr[ks],  rR0, 0, 0, 0);
            rR0 = __builtin_amdgcn_mfma_f32_16x16x32_bf16(aI0, bEiN[ks], rR0, 0, 0, 0);
            rI0 = __builtin_amdgcn_mfma_f32_16x16x32_bf16(aR0, bEi_,     rI0, 0, 0, 0);
            rI0 = __builtin_amdgcn_mfma_f32_16x16x32_bf16(aI0, bEr[ks],  rI0, 0, 0, 0);
            rR1 = __builtin_amdgcn_mfma_f32_16x16x32_bf16(aR1, bEr[ks],  rR1, 0, 0, 0);
            rR1 = __builtin_amdgcn_mfma_f32_16x16x32_bf16(aI1, bEiN[ks], rR1, 0, 0, 0);
            rI1 = __builtin_amdgcn_mfma_f32_16x16x32_bf16(aR1, bEi_,     rI1, 0, 0, 0);
            rI1 = __builtin_amdgcn_mfma_f32_16x16x32_bf16(aI1, bEr[ks],  rI1, 0, 0, 0);
        }

        // C += Ey * R_y  (Ey exact from tab; depends only on k=kl)
        const float2 e = tab[0][y][kl];
#pragma unroll
        for (int r = 0; r < 4; ++r) {
            cR0[r] += e.x * rR0[r] - e.y * rI0[r];
            cI0[r] += e.x * rI0[r] + e.y * rR0[r];
            cR1[r] += e.x * rR1[r] - e.y * rI1[r];
            cI1[r] += e.x * rI1[r] + e.y * rR1[r];
        }
    }

    // ---- cross-wave reduction: waves 0,1 write slots 0,1; waves 2,3 add ----
    const int slot = wv & 1;
    if (wv < 2) {
#pragma unroll
        for (int r = 0; r < 4; ++r) {
            const int n0  = g * 4 + r;
            const int i00 = (n0 * 16 + kl) * 2;
            const int i10 = ((n0 + 16) * 16 + kl) * 2;
            red[slot][i00]     = cR0[r];
            red[slot][i00 + 1] = cI0[r];
            red[slot][i10]     = cR1[r];
            red[slot][i10 + 1] = cI1[r];
        }
    }
    __syncthreads();
    if (wv >= 2) {
#pragma unroll
        for (int r = 0; r < 4; ++r) {
            const int n0  = g * 4 + r;
            const int i00 = (n0 * 16 + kl) * 2;
            const int i10 = ((n0 + 16) * 16 + kl) * 2;
            red[slot][i00]     += cR0[r];
            red[slot][i00 + 1] += cI0[r];
            red[slot][i10]     += cR1[r];
            red[slot][i10 + 1] += cI1[r];
        }
    }
    __syncthreads();

    {
        const int bp = ((t * 128 + kt) * 4 + yq) * 1024;
        for (int f = threadIdx.x; f < 1024; f += NTHR)
            part[bp + f] = red[0][f] + red[1][f];
    }
}

// ---------------------------------------------------------------------------
// Kernel 3: sum 4 y-quarter partials, f32 planar output.
// ---------------------------------------------------------------------------
__global__ __launch_bounds__(256)
void reduce_out(const float* __restrict__ part, float* __restrict__ out)
{
    const int gidx = blockIdx.x * 256 + threadIdx.x;  // [0, 131072)
    const int t  = gidx >> 16;
    const int r1 = gidx & 65535;
    const int kt = r1 >> 9;
    const int r2 = r1 & 511;
    const int n  = r2 >> 4;
    const int kl = r2 & 15;

    const int base = ((t * 128 + kt) * 4) * 1024;
    const int fr   = (n * 16 + kl) * 2;
    float re = 0.f, im = 0.f;
#pragma unroll
    for (int yqi = 0; yqi < 4; ++yqi) {
        re += part[base + yqi * 1024 + fr];
        im += part[base + yqi * 1024 + fr + 1];
    }

    const int oi = (t * 32 + n) * 2048 + kt * KT + kl;
    out[oi]           = re;    // real plane
    out[131072 + oi]  = im;    // imag plane
}

extern "C" void kernel_launch(void* const* d_in, const int* in_sizes, int n_in,
                              void* d_out, int out_size, void* d_ws, size_t ws_size,
                              hipStream_t stream) {
    const float* imr  = (const float*)d_in[0];
    const float* imi  = (const float*)d_in[1];
    const float* csr  = (const float*)d_in[2];
    const float* csi  = (const float*)d_in[3];
    const float* traj = (const float*)d_in[4];
    float* out = (float*)d_out;

    unsigned short* mRb = (unsigned short*)d_ws;
    unsigned short* mIb = mRb + MULTI_ELEMS;
    float* part = (float*)((char*)d_ws + PART_OFF);

    make_multi_bf16<<<dim3(1024), dim3(256), 0, stream>>>(imr, imi, csr, csi, mRb, mIb);
    nufft_mfma5<<<dim3(1024), dim3(NTHR), 0, stream>>>(traj, mRb, mIb, part);
    reduce_out<<<dim3(512), dim3(256), 0, stream>>>(part, out);
}

// Round 19
// 68.250 us; speedup vs baseline: 1.1903x; 1.0965x over previous
//
#include <hip/hip_runtime.h>
#include <math.h>

typedef __attribute__((ext_vector_type(8))) short bf16x8;
typedef __attribute__((ext_vector_type(4))) float f32x4;

#define NK   2048
#define KT   16
#define NTHR 256   // 4 waves

// ws: mRb bf16[1M] @0 (2MB), mIb @2MB (2MB), part f32[1024*1024] @4MB (4MB)
#define MULTI_ELEMS (1 << 20)
#define PART_OFF    (4u << 20)

__device__ __forceinline__ unsigned short f2bf(float f) {
    union { float f; unsigned u; } v; v.f = f;
    const unsigned r = (v.u + 0x7fffu + ((v.u >> 16) & 1u)) >> 16;  // RNE
    return (unsigned short)r;
}

// ---------------------------------------------------------------------------
// Kernel 1: multi = image*csm -> bf16 planes (proven R12-R17, verbatim)
// ---------------------------------------------------------------------------
__global__ __launch_bounds__(256)
void make_multi_bf16(const float* __restrict__ imr, const float* __restrict__ imi,
                     const float* __restrict__ csr, const float* __restrict__ csi,
                     unsigned short* __restrict__ mRb, unsigned short* __restrict__ mIb)
{
    const int gid = blockIdx.x * 256 + threadIdx.x;
    const int p   = gid * 4;
    const int x   = p & 127;
    const int y   = (p >> 7) & 127;
    const int n   = (p >> 14) & 31;
    const int t   = p >> 19;
    const int d   = n & 3;
    const int ch  = n >> 2;
    const int io  = ((t * 4 + d) * 128 + y) * 128 + x;
    const int co  = (((t * 8 + ch) * 4 + d) * 128 + y) * 128 + x;

    const float4 ar = *(const float4*)(imr + io);
    const float4 ai = *(const float4*)(imi + io);
    const float4 br = *(const float4*)(csr + co);
    const float4 bi = *(const float4*)(csi + co);

    ushort4 sr, si;
    sr.x = f2bf(ar.x*br.x - ai.x*bi.x);  si.x = f2bf(ar.x*bi.x + ai.x*br.x);
    sr.y = f2bf(ar.y*br.y - ai.y*bi.y);  si.y = f2bf(ar.y*bi.y + ai.y*br.y);
    sr.z = f2bf(ar.z*br.z - ai.z*bi.z);  si.z = f2bf(ar.z*bi.z + ai.z*br.z);
    sr.w = f2bf(ar.w*br.w - ai.w*bi.w);  si.w = f2bf(ar.w*bi.w + ai.w*br.w);
    *(ushort4*)(mRb + p) = sr;
    *(ushort4*)(mIb + p) = si;
}

// ---------------------------------------------------------------------------
// Kernel 2: R17 structure with LDS-STAGED A. Waves share each y (wave wv owns
// k-slice ks=wv); per y the block stages the y-row [32n][128x]x2ri (16 KB)
// into LDS with coalesced 16B loads, then lanes ds_read their fragments.
// Producer planes + all math/reduction verbatim R17 (proven).
// Lane maps (HW-proven R13/R14/R17): A row=kl(/+16); B col=kl; C row=g*4+r,
// col=kl. Grid 1024 = 2t x 128kt x 4 y-quarters.
// ---------------------------------------------------------------------------
__global__ __launch_bounds__(NTHR, 4)
void nufft_mfma7(const float* __restrict__ traj,
                 const unsigned short* __restrict__ mRb,
                 const unsigned short* __restrict__ mIb,
                 float* __restrict__ part)
{
    __shared__ float2 tab[2][128][16];           // Ey/Ex tables (32 KB)
    __shared__ unsigned short aLds[2][32][136];  // staged y-row, padded (17 KB)
    __shared__ float red[2][1024];               // cross-wave reduction (8 KB)

    const int b   = blockIdx.x;          // [0, 1024)
    const int xcd = b & 7;               // XCD swizzle: 0-3 -> t=0, 4-7 -> t=1
    const int t   = xcd >> 2;
    const int idx = (xcd & 3) * 128 + (b >> 3);  // bijective [0,512)
    const int kt  = idx >> 2;
    const int yq  = idx & 3;             // y-quarter
    const int k0  = kt * KT;
    const int tid = threadIdx.x;

    // ---- tables: exp(-i * kv * (c-64)) (R13/R17 verbatim) ----
    for (int i = tid; i < 2 * 128 * KT; i += NTHR) {
        const int ax  = i >> 11;         // 0=y (ky), 1=x (kx)
        const int rem = i & 2047;
        const int c   = rem >> 4;
        const int kli = rem & 15;
        const float kv = traj[(t * 2 + ax) * NK + k0 + kli];
        float s, co;
        sincosf(-kv * (float)(c - 64), &s, &co);
        tab[ax][c][kli] = make_float2(co, s);
    }
    __syncthreads();

    const int wv = tid >> 6;             // 0..3 = this wave's ks
    const int l  = tid & 63;
    const int kl = l & 15;
    const int g  = l >> 4;
    const int xw = wv * 32 + g * 8;      // this lane's x-offset in the y-row

    // ---- B frag for ks = wv only: Ex[k0+kl][x = wv*32 + g*8 + j] ----
    bf16x8 bEr, bEiN, bEi;
#pragma unroll
    for (int j = 0; j < 8; ++j) {
        const float2 ex = tab[1][xw + j][kl];
        bEr[j]  = (short)f2bf(ex.x);
        bEiN[j] = (short)f2bf(-ex.y);
        bEi[j]  = (short)(bEiN[j] ^ (short)0x8000);
    }

    f32x4 cR0 = {0.f,0.f,0.f,0.f}, cI0 = {0.f,0.f,0.f,0.f};
    f32x4 cR1 = {0.f,0.f,0.f,0.f}, cI1 = {0.f,0.f,0.f,0.f};

    for (int yi = 0; yi < 32; ++yi) {
        const int y = yq * 32 + yi;

        // ---- stage y-row [32n][128x] x 2ri into LDS (coalesced 16B) ----
#pragma unroll
        for (int q = 0; q < 2; ++q) {
            const int s = (q * 256 + tid) * 8;   // [0, 4096), step 8
            const int n = s >> 7;
            const int x = s & 127;
            const size_t go = (((size_t)(t * 32 + n)) << 14) + y * 128 + x;
            *(bf16x8*)&aLds[0][n][x] = *(const bf16x8*)(mRb + go);
            *(bf16x8*)&aLds[1][n][x] = *(const bf16x8*)(mIb + go);
        }
        __syncthreads();

        const bf16x8 aR0 = *(const bf16x8*)&aLds[0][kl][xw];
        const bf16x8 aI0 = *(const bf16x8*)&aLds[1][kl][xw];
        const bf16x8 aR1 = *(const bf16x8*)&aLds[0][kl + 16][xw];
        const bf16x8 aI1 = *(const bf16x8*)&aLds[1][kl + 16][xw];

        f32x4 rR0 = {0.f,0.f,0.f,0.f}, rI0 = {0.f,0.f,0.f,0.f};
        f32x4 rR1 = {0.f,0.f,0.f,0.f}, rI1 = {0.f,0.f,0.f,0.f};

        rR0 = __builtin_amdgcn_mfma_f32_16x16x32_bf16(aR0, bEr,  rR0, 0, 0, 0);
        rR0 = __builtin_amdgcn_mfma_f32_16x16x32_bf16(aI0, bEiN, rR0, 0, 0, 0);
        rI0 = __builtin_amdgcn_mfma_f32_16x16x32_bf16(aR0, bEi,  rI0, 0, 0, 0);
        rI0 = __builtin_amdgcn_mfma_f32_16x16x32_bf16(aI0, bEr,  rI0, 0, 0, 0);
        rR1 = __builtin_amdgcn_mfma_f32_16x16x32_bf16(aR1, bEr,  rR1, 0, 0, 0);
        rR1 = __builtin_amdgcn_mfma_f32_16x16x32_bf16(aI1, bEiN, rR1, 0, 0, 0);
        rI1 = __builtin_amdgcn_mfma_f32_16x16x32_bf16(aR1, bEi,  rI1, 0, 0, 0);
        rI1 = __builtin_amdgcn_mfma_f32_16x16x32_bf16(aI1, bEr,  rI1, 0, 0, 0);

        // C += Ey * R_y  (Ey exact from tab; depends only on k=kl)
        const float2 e = tab[0][y][kl];
#pragma unroll
        for (int r = 0; r < 4; ++r) {
            cR0[r] += e.x * rR0[r] - e.y * rI0[r];
            cI0[r] += e.x * rI0[r] + e.y * rR0[r];
            cR1[r] += e.x * rR1[r] - e.y * rI1[r];
            cI1[r] += e.x * rI1[r] + e.y * rR1[r];
        }
        __syncthreads();   // protect aLds before next y's stage
    }

    // ---- cross-wave reduction (verbatim R17; sums the 4 ks partials) ----
    const int slot = wv & 1;
    if (wv < 2) {
#pragma unroll
        for (int r = 0; r < 4; ++r) {
            const int n0  = g * 4 + r;
            const int i00 = (n0 * 16 + kl) * 2;
            const int i10 = ((n0 + 16) * 16 + kl) * 2;
            red[slot][i00]     = cR0[r];
            red[slot][i00 + 1] = cI0[r];
            red[slot][i10]     = cR1[r];
            red[slot][i10 + 1] = cI1[r];
        }
    }
    __syncthreads();
    if (wv >= 2) {
#pragma unroll
        for (int r = 0; r < 4; ++r) {
            const int n0  = g * 4 + r;
            const int i00 = (n0 * 16 + kl) * 2;
            const int i10 = ((n0 + 16) * 16 + kl) * 2;
            red[slot][i00]     += cR0[r];
            red[slot][i00 + 1] += cI0[r];
            red[slot][i10]     += cR1[r];
            red[slot][i10 + 1] += cI1[r];
        }
    }
    __syncthreads();

    {
        const int bp = ((t * 128 + kt) * 4 + yq) * 1024;
        for (int f = tid; f < 1024; f += NTHR)
            part[bp + f] = red[0][f] + red[1][f];
    }
}

// ---------------------------------------------------------------------------
// Kernel 3: sum 4 y-quarter partials, f32 planar output (verbatim R17).
// ---------------------------------------------------------------------------
__global__ __launch_bounds__(256)
void reduce_out(const float* __restrict__ part, float* __restrict__ out)
{
    const int gidx = blockIdx.x * 256 + threadIdx.x;  // [0, 131072)
    const int t  = gidx >> 16;
    const int r1 = gidx & 65535;
    const int kt = r1 >> 9;
    const int r2 = r1 & 511;
    const int n  = r2 >> 4;
    const int kl = r2 & 15;

    const int base = ((t * 128 + kt) * 4) * 1024;
    const int fr   = (n * 16 + kl) * 2;
    float re = 0.f, im = 0.f;
#pragma unroll
    for (int yqi = 0; yqi < 4; ++yqi) {
        re += part[base + yqi * 1024 + fr];
        im += part[base + yqi * 1024 + fr + 1];
    }

    const int oi = (t * 32 + n) * 2048 + kt * KT + kl;
    out[oi]           = re;    // real plane
    out[131072 + oi]  = im;    // imag plane
}

extern "C" void kernel_launch(void* const* d_in, const int* in_sizes, int n_in,
                              void* d_out, int out_size, void* d_ws, size_t ws_size,
                              hipStream_t stream) {
    const float* imr  = (const float*)d_in[0];
    const float* imi  = (const float*)d_in[1];
    const float* csr  = (const float*)d_in[2];
    const float* csi  = (const float*)d_in[3];
    const float* traj = (const float*)d_in[4];
    float* out = (float*)d_out;

    unsigned short* mRb = (unsigned short*)d_ws;
    unsigned short* mIb = mRb + MULTI_ELEMS;
    float* part = (float*)((char*)d_ws + PART_OFF);

    make_multi_bf16<<<dim3(1024), dim3(256), 0, stream>>>(imr, imi, csr, csi, mRb, mIb);
    nufft_mfma7<<<dim3(1024), dim3(NTHR), 0, stream>>>(traj, mRb, mIb, part);
    reduce_out<<<dim3(512), dim3(256), 0, stream>>>(part, out);
}

// Round 22
// 61.902 us; speedup vs baseline: 1.3123x; 1.1025x over previous
//
#include <hip/hip_runtime.h>
#include <math.h>

typedef __attribute__((ext_vector_type(8))) short bf16x8;
typedef __attribute__((ext_vector_type(4))) float f32x4;

#define NK   2048
#define KT   16
#define NTHR 256   // 4 waves

// ws: mRb bf16[1M] @0 (2MB), mIb @2MB (2MB), part f32[1024*1024] @4MB (4MB)
#define MULTI_ELEMS (1 << 20)
#define PART_OFF    (4u << 20)

__device__ __forceinline__ unsigned short f2bf(float f) {
    union { float f; unsigned u; } v; v.f = f;
    const unsigned r = (v.u + 0x7fffu + ((v.u >> 16) & 1u)) >> 16;  // RNE
    return (unsigned short)r;
}

// ---------------------------------------------------------------------------
// Kernel 1: multi = image*csm -> bf16 planes (proven R12-R19, verbatim)
// ---------------------------------------------------------------------------
__global__ __launch_bounds__(256)
void make_multi_bf16(const float* __restrict__ imr, const float* __restrict__ imi,
                     const float* __restrict__ csr, const float* __restrict__ csi,
                     unsigned short* __restrict__ mRb, unsigned short* __restrict__ mIb)
{
    const int gid = blockIdx.x * 256 + threadIdx.x;
    const int p   = gid * 4;
    const int x   = p & 127;
    const int y   = (p >> 7) & 127;
    const int n   = (p >> 14) & 31;
    const int t   = p >> 19;
    const int d   = n & 3;
    const int ch  = n >> 2;
    const int io  = ((t * 4 + d) * 128 + y) * 128 + x;
    const int co  = (((t * 8 + ch) * 4 + d) * 128 + y) * 128 + x;

    const float4 ar = *(const float4*)(imr + io);
    const float4 ai = *(const float4*)(imi + io);
    const float4 br = *(const float4*)(csr + co);
    const float4 bi = *(const float4*)(csi + co);

    ushort4 sr, si;
    sr.x = f2bf(ar.x*br.x - ai.x*bi.x);  si.x = f2bf(ar.x*bi.x + ai.x*br.x);
    sr.y = f2bf(ar.y*br.y - ai.y*bi.y);  si.y = f2bf(ar.y*bi.y + ai.y*br.y);
    sr.z = f2bf(ar.z*br.z - ai.z*bi.z);  si.z = f2bf(ar.z*bi.z + ai.z*br.z);
    sr.w = f2bf(ar.w*br.w - ai.w*bi.w);  si.w = f2bf(ar.w*bi.w + ai.w*br.w);
    *(ushort4*)(mRb + p) = sr;
    *(ushort4*)(mIb + p) = si;
}

// ---------------------------------------------------------------------------
// Kernel 2: R19 verbatim except aLds holds TWO y-rows per stage (rows
// [0,32)=y0, [32,64)=y0+1); compute body duplicated inline for the two y's.
// Protocol unchanged: stage -> barrier -> compute -> barrier. tab/B/MFMA/
// reduction verbatim R19. Grid 1024 = 2t x 128kt x 4 y-quarters; wave wv
// owns k-slice ks=wv. Lane maps HW-proven R13-R19.
// ---------------------------------------------------------------------------
__global__ __launch_bounds__(NTHR, 4)
void nufft_mfma10(const float* __restrict__ traj,
                  const unsigned short* __restrict__ mRb,
                  const unsigned short* __restrict__ mIb,
                  float* __restrict__ part)
{
    __shared__ float2 tab[2][128][16];           // Ey/Ex tables (32 KB, R19)
    __shared__ unsigned short aLds[2][64][136];  // 2 staged y-rows (35 KB)
    __shared__ float red[2][1024];               // cross-wave reduction (8 KB)

    const int b   = blockIdx.x;          // [0, 1024)
    const int xcd = b & 7;               // XCD swizzle: 0-3 -> t=0, 4-7 -> t=1
    const int t   = xcd >> 2;
    const int idx = (xcd & 3) * 128 + (b >> 3);  // bijective [0,512)
    const int kt  = idx >> 2;
    const int yq  = idx & 3;             // y-quarter
    const int k0  = kt * KT;
    const int tid = threadIdx.x;

    // ---- tables: exp(-i * kv * (c-64)) (R13/R17/R19 verbatim) ----
    for (int i = tid; i < 2 * 128 * KT; i += NTHR) {
        const int ax  = i >> 11;         // 0=y (ky), 1=x (kx)
        const int rem = i & 2047;
        const int c   = rem >> 4;
        const int kli = rem & 15;
        const float kv = traj[(t * 2 + ax) * NK + k0 + kli];
        float s, co;
        sincosf(-kv * (float)(c - 64), &s, &co);
        tab[ax][c][kli] = make_float2(co, s);
    }
    __syncthreads();

    const int wv = tid >> 6;             // 0..3 = this wave's ks
    const int l  = tid & 63;
    const int kl = l & 15;
    const int g  = l >> 4;
    const int xw = wv * 32 + g * 8;      // lane's x-offset in the y-row

    // ---- B frag for ks = wv from tab (R19 verbatim) ----
    bf16x8 bEr, bEiN, bEi;
#pragma unroll
    for (int j = 0; j < 8; ++j) {
        const float2 ex = tab[1][xw + j][kl];
        bEr[j]  = (short)f2bf(ex.x);
        bEiN[j] = (short)f2bf(-ex.y);
        bEi[j]  = (short)(bEiN[j] ^ (short)0x8000);
    }

    f32x4 cR0 = {0.f,0.f,0.f,0.f}, cI0 = {0.f,0.f,0.f,0.f};
    f32x4 cR1 = {0.f,0.f,0.f,0.f}, cI1 = {0.f,0.f,0.f,0.f};

    for (int pp = 0; pp < 16; ++pp) {
        const int y0 = yq * 32 + pp * 2;

        // ---- stage TWO y-rows: aLds[ri][yy*32+n][x], yy = row>>5 ----
#pragma unroll
        for (int q = 0; q < 4; ++q) {
            const int s  = (q * 256 + tid) * 8;   // [0, 8192), step 8
            const int nr = s >> 7;                // 0..63
            const int x  = s & 127;
            const int n  = nr & 31;
            const int yy = nr >> 5;
            const size_t go = (((size_t)(t * 32 + n)) << 14) + (y0 + yy) * 128 + x;
            *(bf16x8*)&aLds[0][nr][x] = *(const bf16x8*)(mRb + go);
            *(bf16x8*)&aLds[1][nr][x] = *(const bf16x8*)(mIb + go);
        }
        __syncthreads();

        // ======== body for y = y0 (rows +0) — R19 verbatim ========
        {
            const bf16x8 aR0 = *(const bf16x8*)&aLds[0][kl][xw];
            const bf16x8 aI0 = *(const bf16x8*)&aLds[1][kl][xw];
            const bf16x8 aR1 = *(const bf16x8*)&aLds[0][kl + 16][xw];
            const bf16x8 aI1 = *(const bf16x8*)&aLds[1][kl + 16][xw];

            f32x4 rR0 = {0.f,0.f,0.f,0.f}, rI0 = {0.f,0.f,0.f,0.f};
            f32x4 rR1 = {0.f,0.f,0.f,0.f}, rI1 = {0.f,0.f,0.f,0.f};

            rR0 = __builtin_amdgcn_mfma_f32_16x16x32_bf16(aR0, bEr,  rR0, 0, 0, 0);
            rR0 = __builtin_amdgcn_mfma_f32_16x16x32_bf16(aI0, bEiN, rR0, 0, 0, 0);
            rI0 = __builtin_amdgcn_mfma_f32_16x16x32_bf16(aR0, bEi,  rI0, 0, 0, 0);
            rI0 = __builtin_amdgcn_mfma_f32_16x16x32_bf16(aI0, bEr,  rI0, 0, 0, 0);
            rR1 = __builtin_amdgcn_mfma_f32_16x16x32_bf16(aR1, bEr,  rR1, 0, 0, 0);
            rR1 = __builtin_amdgcn_mfma_f32_16x16x32_bf16(aI1, bEiN, rR1, 0, 0, 0);
            rI1 = __builtin_amdgcn_mfma_f32_16x16x32_bf16(aR1, bEi,  rI1, 0, 0, 0);
            rI1 = __builtin_amdgcn_mfma_f32_16x16x32_bf16(aI1, bEr,  rI1, 0, 0, 0);

            const float2 e = tab[0][y0][kl];
#pragma unroll
            for (int r = 0; r < 4; ++r) {
                cR0[r] += e.x * rR0[r] - e.y * rI0[r];
                cI0[r] += e.x * rI0[r] + e.y * rR0[r];
                cR1[r] += e.x * rR1[r] - e.y * rI1[r];
                cI1[r] += e.x * rI1[r] + e.y * rR1[r];
            }
        }

        // ======== body for y = y0+1 (rows +32) — R19 verbatim ========
        {
            const bf16x8 aR0 = *(const bf16x8*)&aLds[0][32 + kl][xw];
            const bf16x8 aI0 = *(const bf16x8*)&aLds[1][32 + kl][xw];
            const bf16x8 aR1 = *(const bf16x8*)&aLds[0][32 + kl + 16][xw];
            const bf16x8 aI1 = *(const bf16x8*)&aLds[1][32 + kl + 16][xw];

            f32x4 rR0 = {0.f,0.f,0.f,0.f}, rI0 = {0.f,0.f,0.f,0.f};
            f32x4 rR1 = {0.f,0.f,0.f,0.f}, rI1 = {0.f,0.f,0.f,0.f};

            rR0 = __builtin_amdgcn_mfma_f32_16x16x32_bf16(aR0, bEr,  rR0, 0, 0, 0);
            rR0 = __builtin_amdgcn_mfma_f32_16x16x32_bf16(aI0, bEiN, rR0, 0, 0, 0);
            rI0 = __builtin_amdgcn_mfma_f32_16x16x32_bf16(aR0, bEi,  rI0, 0, 0, 0);
            rI0 = __builtin_amdgcn_mfma_f32_16x16x32_bf16(aI0, bEr,  rI0, 0, 0, 0);
            rR1 = __builtin_amdgcn_mfma_f32_16x16x32_bf16(aR1, bEr,  rR1, 0, 0, 0);
            rR1 = __builtin_amdgcn_mfma_f32_16x16x32_bf16(aI1, bEiN, rR1, 0, 0, 0);
            rI1 = __builtin_amdgcn_mfma_f32_16x16x32_bf16(aR1, bEi,  rI1, 0, 0, 0);
            rI1 = __builtin_amdgcn_mfma_f32_16x16x32_bf16(aI1, bEr,  rI1, 0, 0, 0);

            const float2 e = tab[0][y0 + 1][kl];
#pragma unroll
            for (int r = 0; r < 4; ++r) {
                cR0[r] += e.x * rR0[r] - e.y * rI0[r];
                cI0[r] += e.x * rI0[r] + e.y * rR0[r];
                cR1[r] += e.x * rR1[r] - e.y * rI1[r];
                cI1[r] += e.x * rI1[r] + e.y * rR1[r];
            }
        }
        __syncthreads();   // protect aLds before next stage
    }

    // ---- cross-wave reduction (verbatim R17/R19) ----
    const int slot = wv & 1;
    if (wv < 2) {
#pragma unroll
        for (int r = 0; r < 4; ++r) {
            const int nn  = g * 4 + r;
            const int i00 = (nn * 16 + kl) * 2;
            const int i10 = ((nn + 16) * 16 + kl) * 2;
            red[slot][i00]     = cR0[r];
            red[slot][i00 + 1] = cI0[r];
            red[slot][i10]     = cR1[r];
            red[slot][i10 + 1] = cI1[r];
        }
    }
    __syncthreads();
    if (wv >= 2) {
#pragma unroll
        for (int r = 0; r < 4; ++r) {
            const int nn  = g * 4 + r;
            const int i00 = (nn * 16 + kl) * 2;
            const int i10 = ((nn + 16) * 16 + kl) * 2;
            red[slot][i00]     += cR0[r];
            red[slot][i00 + 1] += cI0[r];
            red[slot][i10]     += cR1[r];
            red[slot][i10 + 1] += cI1[r];
        }
    }
    __syncthreads();

    {
        const int bp = ((t * 128 + kt) * 4 + yq) * 1024;
        for (int f = tid; f < 1024; f += NTHR)
            part[bp + f] = red[0][f] + red[1][f];
    }
}

// ---------------------------------------------------------------------------
// Kernel 3: sum 4 y-quarter partials, f32 planar output (verbatim R17/R19).
// ---------------------------------------------------------------------------
__global__ __launch_bounds__(256)
void reduce_out(const float* __restrict__ part, float* __restrict__ out)
{
    const int gidx = blockIdx.x * 256 + threadIdx.x;  // [0, 131072)
    const int t  = gidx >> 16;
    const int r1 = gidx & 65535;
    const int kt = r1 >> 9;
    const int r2 = r1 & 511;
    const int n  = r2 >> 4;
    const int kl = r2 & 15;

    const int base = ((t * 128 + kt) * 4) * 1024;
    const int fr   = (n * 16 + kl) * 2;
    float re = 0.f, im = 0.f;
#pragma unroll
    for (int yqi = 0; yqi < 4; ++yqi) {
        re += part[base + yqi * 1024 + fr];
        im += part[base + yqi * 1024 + fr + 1];
    }

    const int oi = (t * 32 + n) * 2048 + kt * KT + kl;
    out[oi]           = re;    // real plane
    out[131072 + oi]  = im;    // imag plane
}

extern "C" void kernel_launch(void* const* d_in, const int* in_sizes, int n_in,
                              void* d_out, int out_size, void* d_ws, size_t ws_size,
                              hipStream_t stream) {
    const float* imr  = (const float*)d_in[0];
    const float* imi  = (const float*)d_in[1];
    const float* csr  = (const float*)d_in[2];
    const float* csi  = (const float*)d_in[3];
    const float* traj = (const float*)d_in[4];
    float* out = (float*)d_out;

    unsigned short* mRb = (unsigned short*)d_ws;
    unsigned short* mIb = mRb + MULTI_ELEMS;
    float* part = (float*)((char*)d_ws + PART_OFF);

    make_multi_bf16<<<dim3(1024), dim3(256), 0, stream>>>(imr, imi, csr, csi, mRb, mIb);
    nufft_mfma10<<<dim3(1024), dim3(NTHR), 0, stream>>>(traj, mRb, mIb, part);
    reduce_out<<<dim3(512), dim3(256), 0, stream>>>(part, out);
}

// Round 23
// 60.365 us; speedup vs baseline: 1.3457x; 1.0255x over previous
//
#include <hip/hip_runtime.h>
#include <math.h>

typedef __attribute__((ext_vector_type(8))) short bf16x8;
typedef __attribute__((ext_vector_type(4))) float f32x4;

#define NK   2048
#define KT   16
#define NTHR 256   // 4 waves

// ws: mRb bf16[1M] @0 (2MB), mIb @2MB (2MB), part f32[1024*1024] @4MB (4MB)
#define MULTI_ELEMS (1 << 20)
#define PART_OFF    (4u << 20)

__device__ __forceinline__ unsigned short f2bf(float f) {
    union { float f; unsigned u; } v; v.f = f;
    const unsigned r = (v.u + 0x7fffu + ((v.u >> 16) & 1u)) >> 16;  // RNE
    return (unsigned short)r;
}

// ---------------------------------------------------------------------------
// Kernel 1: multi = image*csm -> bf16 planes (proven R12-R22, verbatim)
// ---------------------------------------------------------------------------
__global__ __launch_bounds__(256)
void make_multi_bf16(const float* __restrict__ imr, const float* __restrict__ imi,
                     const float* __restrict__ csr, const float* __restrict__ csi,
                     unsigned short* __restrict__ mRb, unsigned short* __restrict__ mIb)
{
    const int gid = blockIdx.x * 256 + threadIdx.x;
    const int p   = gid * 4;
    const int x   = p & 127;
    const int y   = (p >> 7) & 127;
    const int n   = (p >> 14) & 31;
    const int t   = p >> 19;
    const int d   = n & 3;
    const int ch  = n >> 2;
    const int io  = ((t * 4 + d) * 128 + y) * 128 + x;
    const int co  = (((t * 8 + ch) * 4 + d) * 128 + y) * 128 + x;

    const float4 ar = *(const float4*)(imr + io);
    const float4 ai = *(const float4*)(imi + io);
    const float4 br = *(const float4*)(csr + co);
    const float4 bi = *(const float4*)(csi + co);

    ushort4 sr, si;
    sr.x = f2bf(ar.x*br.x - ai.x*bi.x);  si.x = f2bf(ar.x*bi.x + ai.x*br.x);
    sr.y = f2bf(ar.y*br.y - ai.y*bi.y);  si.y = f2bf(ar.y*bi.y + ai.y*br.y);
    sr.z = f2bf(ar.z*br.z - ai.z*bi.z);  si.z = f2bf(ar.z*bi.z + ai.z*br.z);
    sr.w = f2bf(ar.w*br.w - ai.w*bi.w);  si.w = f2bf(ar.w*bi.w + ai.w*br.w);
    *(ushort4*)(mRb + p) = sr;
    *(ushort4*)(mIb + p) = si;
}

// ---------------------------------------------------------------------------
// Kernel 2: R22 verbatim, LDS reorganized for occupancy (51.2 KB -> 3 blk/CU):
//   [0,16K):   eyT[128][16]  — permanent Ey table (same build/values as R22)
//   [16K,51K): aLds[2][64][136] — staged 2 y-rows; TRANSIENTLY holds
//              exT[128][16] during the prologue (B-frag source), and red[2][1024]
//              after the main loop. All transitions barrier-separated
//              (aliasing pattern proven in R12).
// Grid 1024 = 2t x 128kt x 4 y-quarters; wave wv owns k-slice ks=wv.
// Lane maps HW-proven R13-R22.
// ---------------------------------------------------------------------------
__global__ __launch_bounds__(NTHR, 4)
void nufft_mfma11(const float* __restrict__ traj,
                  const unsigned short* __restrict__ mRb,
                  const unsigned short* __restrict__ mIb,
                  float* __restrict__ part)
{
    __shared__ __align__(16) unsigned char sm[16384 + 2 * 64 * 136 * 2];  // 51200 B
    float2 (*eyT)[16] = reinterpret_cast<float2 (*)[16]>(sm);                     // [128][16]
    float2 (*exT)[16] = reinterpret_cast<float2 (*)[16]>(sm + 16384);             // [128][16] transient
    unsigned short (*aLds)[64][136] =
        reinterpret_cast<unsigned short (*)[64][136]>(sm + 16384);                // [2][64][136]
    float (*red)[1024] = reinterpret_cast<float (*)[1024]>(sm + 16384);           // [2][1024] post-loop

    const int b   = blockIdx.x;          // [0, 1024)
    const int xcd = b & 7;               // XCD swizzle: 0-3 -> t=0, 4-7 -> t=1
    const int t   = xcd >> 2;
    const int idx = (xcd & 3) * 128 + (b >> 3);  // bijective [0,512)
    const int kt  = idx >> 2;
    const int yq  = idx & 3;             // y-quarter
    const int k0  = kt * KT;
    const int tid = threadIdx.x;

    // ---- tables: exp(-i * kv * (c-64)) — same loop/values as R22's tab ----
    for (int i = tid; i < 2 * 128 * KT; i += NTHR) {
        const int ax  = i >> 11;         // 0=y (ky), 1=x (kx)
        const int rem = i & 2047;
        const int c   = rem >> 4;
        const int kli = rem & 15;
        const float kv = traj[(t * 2 + ax) * NK + k0 + kli];
        float s, co;
        sincosf(-kv * (float)(c - 64), &s, &co);
        if (ax == 0) eyT[c][kli] = make_float2(co, s);
        else         exT[c][kli] = make_float2(co, s);
    }
    __syncthreads();

    const int wv = tid >> 6;             // 0..3 = this wave's ks
    const int l  = tid & 63;
    const int kl = l & 15;
    const int g  = l >> 4;
    const int xw = wv * 32 + g * 8;      // lane's x-offset in the y-row

    // ---- B frag for ks = wv from exT (same formula/values as R22) ----
    bf16x8 bEr, bEiN, bEi;
#pragma unroll
    for (int j = 0; j < 8; ++j) {
        const float2 ex = exT[xw + j][kl];
        bEr[j]  = (short)f2bf(ex.x);
        bEiN[j] = (short)f2bf(-ex.y);
        bEi[j]  = (short)(bEiN[j] ^ (short)0x8000);
    }
    __syncthreads();   // all waves done reading exT before staging overwrites it

    f32x4 cR0 = {0.f,0.f,0.f,0.f}, cI0 = {0.f,0.f,0.f,0.f};
    f32x4 cR1 = {0.f,0.f,0.f,0.f}, cI1 = {0.f,0.f,0.f,0.f};

    for (int pp = 0; pp < 16; ++pp) {
        const int y0 = yq * 32 + pp * 2;

        // ---- stage TWO y-rows (R22 verbatim): aLds[ri][yy*32+n][x] ----
#pragma unroll
        for (int q = 0; q < 4; ++q) {
            const int s  = (q * 256 + tid) * 8;   // [0, 8192), step 8
            const int nr = s >> 7;                // 0..63
            const int x  = s & 127;
            const int n  = nr & 31;
            const int yy = nr >> 5;
            const size_t go = (((size_t)(t * 32 + n)) << 14) + (y0 + yy) * 128 + x;
            *(bf16x8*)&aLds[0][nr][x] = *(const bf16x8*)(mRb + go);
            *(bf16x8*)&aLds[1][nr][x] = *(const bf16x8*)(mIb + go);
        }
        __syncthreads();

        // ======== body for y = y0 (rows +0) — R22 verbatim ========
        {
            const bf16x8 aR0 = *(const bf16x8*)&aLds[0][kl][xw];
            const bf16x8 aI0 = *(const bf16x8*)&aLds[1][kl][xw];
            const bf16x8 aR1 = *(const bf16x8*)&aLds[0][kl + 16][xw];
            const bf16x8 aI1 = *(const bf16x8*)&aLds[1][kl + 16][xw];

            f32x4 rR0 = {0.f,0.f,0.f,0.f}, rI0 = {0.f,0.f,0.f,0.f};
            f32x4 rR1 = {0.f,0.f,0.f,0.f}, rI1 = {0.f,0.f,0.f,0.f};

            rR0 = __builtin_amdgcn_mfma_f32_16x16x32_bf16(aR0, bEr,  rR0, 0, 0, 0);
            rR0 = __builtin_amdgcn_mfma_f32_16x16x32_bf16(aI0, bEiN, rR0, 0, 0, 0);
            rI0 = __builtin_amdgcn_mfma_f32_16x16x32_bf16(aR0, bEi,  rI0, 0, 0, 0);
            rI0 = __builtin_amdgcn_mfma_f32_16x16x32_bf16(aI0, bEr,  rI0, 0, 0, 0);
            rR1 = __builtin_amdgcn_mfma_f32_16x16x32_bf16(aR1, bEr,  rR1, 0, 0, 0);
            rR1 = __builtin_amdgcn_mfma_f32_16x16x32_bf16(aI1, bEiN, rR1, 0, 0, 0);
            rI1 = __builtin_amdgcn_mfma_f32_16x16x32_bf16(aR1, bEi,  rI1, 0, 0, 0);
            rI1 = __builtin_amdgcn_mfma_f32_16x16x32_bf16(aI1, bEr,  rI1, 0, 0, 0);

            const float2 e = eyT[y0][kl];
#pragma unroll
            for (int r = 0; r < 4; ++r) {
                cR0[r] += e.x * rR0[r] - e.y * rI0[r];
                cI0[r] += e.x * rI0[r] + e.y * rR0[r];
                cR1[r] += e.x * rR1[r] - e.y * rI1[r];
                cI1[r] += e.x * rI1[r] + e.y * rR1[r];
            }
        }

        // ======== body for y = y0+1 (rows +32) — R22 verbatim ========
        {
            const bf16x8 aR0 = *(const bf16x8*)&aLds[0][32 + kl][xw];
            const bf16x8 aI0 = *(const bf16x8*)&aLds[1][32 + kl][xw];
            const bf16x8 aR1 = *(const bf16x8*)&aLds[0][32 + kl + 16][xw];
            const bf16x8 aI1 = *(const bf16x8*)&aLds[1][32 + kl + 16][xw];

            f32x4 rR0 = {0.f,0.f,0.f,0.f}, rI0 = {0.f,0.f,0.f,0.f};
            f32x4 rR1 = {0.f,0.f,0.f,0.f}, rI1 = {0.f,0.f,0.f,0.f};

            rR0 = __builtin_amdgcn_mfma_f32_16x16x32_bf16(aR0, bEr,  rR0, 0, 0, 0);
            rR0 = __builtin_amdgcn_mfma_f32_16x16x32_bf16(aI0, bEiN, rR0, 0, 0, 0);
            rI0 = __builtin_amdgcn_mfma_f32_16x16x32_bf16(aR0, bEi,  rI0, 0, 0, 0);
            rI0 = __builtin_amdgcn_mfma_f32_16x16x32_bf16(aI0, bEr,  rI0, 0, 0, 0);
            rR1 = __builtin_amdgcn_mfma_f32_16x16x32_bf16(aR1, bEr,  rR1, 0, 0, 0);
            rR1 = __builtin_amdgcn_mfma_f32_16x16x32_bf16(aI1, bEiN, rR1, 0, 0, 0);
            rI1 = __builtin_amdgcn_mfma_f32_16x16x32_bf16(aR1, bEi,  rI1, 0, 0, 0);
            rI1 = __builtin_amdgcn_mfma_f32_16x16x32_bf16(aI1, bEr,  rI1, 0, 0, 0);

            const float2 e = eyT[y0 + 1][kl];
#pragma unroll
            for (int r = 0; r < 4; ++r) {
                cR0[r] += e.x * rR0[r] - e.y * rI0[r];
                cI0[r] += e.x * rI0[r] + e.y * rR0[r];
                cR1[r] += e.x * rR1[r] - e.y * rI1[r];
                cI1[r] += e.x * rI1[r] + e.y * rR1[r];
            }
        }
        __syncthreads();   // protect aLds before next stage
    }

    // ---- cross-wave reduction (verbatim R22; red aliases dead aLds) ----
    const int slot = wv & 1;
    if (wv < 2) {
#pragma unroll
        for (int r = 0; r < 4; ++r) {
            const int nn  = g * 4 + r;
            const int i00 = (nn * 16 + kl) * 2;
            const int i10 = ((nn + 16) * 16 + kl) * 2;
            red[slot][i00]     = cR0[r];
            red[slot][i00 + 1] = cI0[r];
            red[slot][i10]     = cR1[r];
            red[slot][i10 + 1] = cI1[r];
        }
    }
    __syncthreads();
    if (wv >= 2) {
#pragma unroll
        for (int r = 0; r < 4; ++r) {
            const int nn  = g * 4 + r;
            const int i00 = (nn * 16 + kl) * 2;
            const int i10 = ((nn + 16) * 16 + kl) * 2;
            red[slot][i00]     += cR0[r];
            red[slot][i00 + 1] += cI0[r];
            red[slot][i10]     += cR1[r];
            red[slot][i10 + 1] += cI1[r];
        }
    }
    __syncthreads();

    {
        const int bp = ((t * 128 + kt) * 4 + yq) * 1024;
        for (int f = tid; f < 1024; f += NTHR)
            part[bp + f] = red[0][f] + red[1][f];
    }
}

// ---------------------------------------------------------------------------
// Kernel 3: sum 4 y-quarter partials, f32 planar output (verbatim R17-R22).
// ---------------------------------------------------------------------------
__global__ __launch_bounds__(256)
void reduce_out(const float* __restrict__ part, float* __restrict__ out)
{
    const int gidx = blockIdx.x * 256 + threadIdx.x;  // [0, 131072)
    const int t  = gidx >> 16;
    const int r1 = gidx & 65535;
    const int kt = r1 >> 9;
    const int r2 = r1 & 511;
    const int n  = r2 >> 4;
    const int kl = r2 & 15;

    const int base = ((t * 128 + kt) * 4) * 1024;
    const int fr   = (n * 16 + kl) * 2;
    float re = 0.f, im = 0.f;
#pragma unroll
    for (int yqi = 0; yqi < 4; ++yqi) {
        re += part[base + yqi * 1024 + fr];
        im += part[base + yqi * 1024 + fr + 1];
    }

    const int oi = (t * 32 + n) * 2048 + kt * KT + kl;
    out[oi]           = re;    // real plane
    out[131072 + oi]  = im;    // imag plane
}

extern "C" void kernel_launch(void* const* d_in, const int* in_sizes, int n_in,
                              void* d_out, int out_size, void* d_ws, size_t ws_size,
                              hipStream_t stream) {
    const float* imr  = (const float*)d_in[0];
    const float* imi  = (const float*)d_in[1];
    const float* csr  = (const float*)d_in[2];
    const float* csi  = (const float*)d_in[3];
    const float* traj = (const float*)d_in[4];
    float* out = (float*)d_out;

    unsigned short* mRb = (unsigned short*)d_ws;
    unsigned short* mIb = mRb + MULTI_ELEMS;
    float* part = (float*)((char*)d_ws + PART_OFF);

    make_multi_bf16<<<dim3(1024), dim3(256), 0, stream>>>(imr, imi, csr, csi, mRb, mIb);
    nufft_mfma11<<<dim3(1024), dim3(NTHR), 0, stream>>>(traj, mRb, mIb, part);
    reduce_out<<<dim3(512), dim3(256), 0, stream>>>(part, out);
}

// Round 24
// 48.440 us; speedup vs baseline: 1.6770x; 1.2462x over previous
//
#include <hip/hip_runtime.h>
#include <math.h>

typedef __attribute__((ext_vector_type(8))) short bf16x8;
typedef __attribute__((ext_vector_type(4))) float f32x4;

#define NK   2048
#define NTHR 256   // 4 waves

// ws: mRb bf16[1M] @0 (2MB), mIb @2MB (2MB), part f32[2*64*4*2048] @4MB (4MB)
#define MULTI_ELEMS (1 << 20)
#define PART_OFF    (4u << 20)

__device__ __forceinline__ unsigned short f2bf(float f) {
    union { float f; unsigned u; } v; v.f = f;
    const unsigned r = (v.u + 0x7fffu + ((v.u >> 16) & 1u)) >> 16;  // RNE
    return (unsigned short)r;
}

// ---------------------------------------------------------------------------
// Kernel 1: multi = image*csm -> bf16 planes (proven R12-R23, verbatim)
// ---------------------------------------------------------------------------
__global__ __launch_bounds__(256)
void make_multi_bf16(const float* __restrict__ imr, const float* __restrict__ imi,
                     const float* __restrict__ csr, const float* __restrict__ csi,
                     unsigned short* __restrict__ mRb, unsigned short* __restrict__ mIb)
{
    const int gid = blockIdx.x * 256 + threadIdx.x;
    const int p   = gid * 4;
    const int x   = p & 127;
    const int y   = (p >> 7) & 127;
    const int n   = (p >> 14) & 31;
    const int t   = p >> 19;
    const int d   = n & 3;
    const int ch  = n >> 2;
    const int io  = ((t * 4 + d) * 128 + y) * 128 + x;
    const int co  = (((t * 8 + ch) * 4 + d) * 128 + y) * 128 + x;

    const float4 ar = *(const float4*)(imr + io);
    const float4 ai = *(const float4*)(imi + io);
    const float4 br = *(const float4*)(csr + co);
    const float4 bi = *(const float4*)(csi + co);

    ushort4 sr, si;
    sr.x = f2bf(ar.x*br.x - ai.x*bi.x);  si.x = f2bf(ar.x*bi.x + ai.x*br.x);
    sr.y = f2bf(ar.y*br.y - ai.y*bi.y);  si.y = f2bf(ar.y*bi.y + ai.y*br.y);
    sr.z = f2bf(ar.z*br.z - ai.z*bi.z);  si.z = f2bf(ar.z*bi.z + ai.z*br.z);
    sr.w = f2bf(ar.w*br.w - ai.w*bi.w);  si.w = f2bf(ar.w*bi.w + ai.w*br.w);
    *(ushort4*)(mRb + p) = sr;
    *(ushort4*)(mIb + p) = si;
}

// ---------------------------------------------------------------------------
// Kernel 2: R23 structure; each block computes TWO kt (32 k) from the same
// staged tile. Grid 512 = 2t x 64 ktp x 4 yq. All patterns proven:
// table loop (constants widened to 32 k), named-reg B/acc duplication (R22
// mold), transient exT + red aliasing in aLds region (R23 mold).
// Lane maps HW-proven R13-R23: A row=kl(/+16); B col=kl; C row=g*4+r, col=kl.
// LDS: eyT[128][32] (32KB) | region{ exT[128][32] (32KB) -> aLds[2][64][136]
// (34.8KB) -> red[2][2048] (16KB) }, barrier-separated. 67.6KB -> 2 blk/CU.
// ---------------------------------------------------------------------------
__global__ __launch_bounds__(NTHR, 2)
void nufft_mfma12(const float* __restrict__ traj,
                  const unsigned short* __restrict__ mRb,
                  const unsigned short* __restrict__ mIb,
                  float* __restrict__ part)
{
    __shared__ __align__(16) unsigned char sm[32768 + 2 * 64 * 136 * 2];  // 67584 B
    float2 (*eyT)[32] = reinterpret_cast<float2 (*)[32]>(sm);                     // [128][32]
    float2 (*exT)[32] = reinterpret_cast<float2 (*)[32]>(sm + 32768);             // [128][32] transient
    unsigned short (*aLds)[64][136] =
        reinterpret_cast<unsigned short (*)[64][136]>(sm + 32768);                // [2][64][136]
    float (*red)[2048] = reinterpret_cast<float (*)[2048]>(sm + 32768);           // [2][2048] post-loop

    const int b   = blockIdx.x;          // [0, 512)
    const int xcd = b & 7;               // XCD swizzle: 0-3 -> t=0, 4-7 -> t=1
    const int t   = xcd >> 2;
    const int idx = (xcd & 3) * 64 + (b >> 3);   // bijective [0,256)
    const int ktp = idx >> 2;            // kt-pair [0,64)
    const int yq  = idx & 3;             // y-quarter
    const int k0  = ktp * 32;
    const int tid = threadIdx.x;

    // ---- tables: exp(-i * kv * (c-64)) for 32 k (R23 loop, widened) ----
    for (int i = tid; i < 2 * 128 * 32; i += NTHR) {
        const int ax  = i >> 12;         // 0=y (ky), 1=x (kx)
        const int rem = i & 4095;
        const int c   = rem >> 5;
        const int kli = rem & 31;
        const float kv = traj[(t * 2 + ax) * NK + k0 + kli];
        float s, co;
        sincosf(-kv * (float)(c - 64), &s, &co);
        if (ax == 0) eyT[c][kli] = make_float2(co, s);
        else         exT[c][kli] = make_float2(co, s);
    }
    __syncthreads();

    const int wv = tid >> 6;             // 0..3 = this wave's x-slice
    const int l  = tid & 63;
    const int kl = l & 15;
    const int g  = l >> 4;
    const int xw = wv * 32 + g * 8;      // lane's x-offset in the y-row

    // ---- B frags for kg=0 (k0+kl) and kg=1 (k0+16+kl), named regs ----
    bf16x8 bEr_a, bEiN_a, bEi_a, bEr_b, bEiN_b, bEi_b;
#pragma unroll
    for (int j = 0; j < 8; ++j) {
        const float2 exa = exT[xw + j][kl];
        bEr_a[j]  = (short)f2bf(exa.x);
        bEiN_a[j] = (short)f2bf(-exa.y);
        bEi_a[j]  = (short)(bEiN_a[j] ^ (short)0x8000);
        const float2 exb = exT[xw + j][16 + kl];
        bEr_b[j]  = (short)f2bf(exb.x);
        bEiN_b[j] = (short)f2bf(-exb.y);
        bEi_b[j]  = (short)(bEiN_b[j] ^ (short)0x8000);
    }
    __syncthreads();   // all waves done reading exT before staging overwrites it

    f32x4 cR0a = {0.f,0.f,0.f,0.f}, cI0a = {0.f,0.f,0.f,0.f};
    f32x4 cR1a = {0.f,0.f,0.f,0.f}, cI1a = {0.f,0.f,0.f,0.f};
    f32x4 cR0b = {0.f,0.f,0.f,0.f}, cI0b = {0.f,0.f,0.f,0.f};
    f32x4 cR1b = {0.f,0.f,0.f,0.f}, cI1b = {0.f,0.f,0.f,0.f};

    for (int pp = 0; pp < 16; ++pp) {
        const int y0 = yq * 32 + pp * 2;

        // ---- stage TWO y-rows (R22/R23 verbatim) ----
#pragma unroll
        for (int q = 0; q < 4; ++q) {
            const int s  = (q * 256 + tid) * 8;   // [0, 8192), step 8
            const int nr = s >> 7;                // 0..63
            const int x  = s & 127;
            const int n  = nr & 31;
            const int yy = nr >> 5;
            const size_t go = (((size_t)(t * 32 + n)) << 14) + (y0 + yy) * 128 + x;
            *(bf16x8*)&aLds[0][nr][x] = *(const bf16x8*)(mRb + go);
            *(bf16x8*)&aLds[1][nr][x] = *(const bf16x8*)(mIb + go);
        }
        __syncthreads();

        // ======== y = y0 (rows +0): kg=a then kg=b — R22 mold ========
        {
            const bf16x8 aR0 = *(const bf16x8*)&aLds[0][kl][xw];
            const bf16x8 aI0 = *(const bf16x8*)&aLds[1][kl][xw];
            const bf16x8 aR1 = *(const bf16x8*)&aLds[0][kl + 16][xw];
            const bf16x8 aI1 = *(const bf16x8*)&aLds[1][kl + 16][xw];

            f32x4 rR0 = {0.f,0.f,0.f,0.f}, rI0 = {0.f,0.f,0.f,0.f};
            f32x4 rR1 = {0.f,0.f,0.f,0.f}, rI1 = {0.f,0.f,0.f,0.f};
            rR0 = __builtin_amdgcn_mfma_f32_16x16x32_bf16(aR0, bEr_a,  rR0, 0, 0, 0);
            rR0 = __builtin_amdgcn_mfma_f32_16x16x32_bf16(aI0, bEiN_a, rR0, 0, 0, 0);
            rI0 = __builtin_amdgcn_mfma_f32_16x16x32_bf16(aR0, bEi_a,  rI0, 0, 0, 0);
            rI0 = __builtin_amdgcn_mfma_f32_16x16x32_bf16(aI0, bEr_a,  rI0, 0, 0, 0);
            rR1 = __builtin_amdgcn_mfma_f32_16x16x32_bf16(aR1, bEr_a,  rR1, 0, 0, 0);
            rR1 = __builtin_amdgcn_mfma_f32_16x16x32_bf16(aI1, bEiN_a, rR1, 0, 0, 0);
            rI1 = __builtin_amdgcn_mfma_f32_16x16x32_bf16(aR1, bEi_a,  rI1, 0, 0, 0);
            rI1 = __builtin_amdgcn_mfma_f32_16x16x32_bf16(aI1, bEr_a,  rI1, 0, 0, 0);
            {
                const float2 e = eyT[y0][kl];
#pragma unroll
                for (int r = 0; r < 4; ++r) {
                    cR0a[r] += e.x * rR0[r] - e.y * rI0[r];
                    cI0a[r] += e.x * rI0[r] + e.y * rR0[r];
                    cR1a[r] += e.x * rR1[r] - e.y * rI1[r];
                    cI1a[r] += e.x * rI1[r] + e.y * rR1[r];
                }
            }

            f32x4 sR0 = {0.f,0.f,0.f,0.f}, sI0 = {0.f,0.f,0.f,0.f};
            f32x4 sR1 = {0.f,0.f,0.f,0.f}, sI1 = {0.f,0.f,0.f,0.f};
            sR0 = __builtin_amdgcn_mfma_f32_16x16x32_bf16(aR0, bEr_b,  sR0, 0, 0, 0);
            sR0 = __builtin_amdgcn_mfma_f32_16x16x32_bf16(aI0, bEiN_b, sR0, 0, 0, 0);
            sI0 = __builtin_amdgcn_mfma_f32_16x16x32_bf16(aR0, bEi_b,  sI0, 0, 0, 0);
            sI0 = __builtin_amdgcn_mfma_f32_16x16x32_bf16(aI0, bEr_b,  sI0, 0, 0, 0);
            sR1 = __builtin_amdgcn_mfma_f32_16x16x32_bf16(aR1, bEr_b,  sR1, 0, 0, 0);
            sR1 = __builtin_amdgcn_mfma_f32_16x16x32_bf16(aI1, bEiN_b, sR1, 0, 0, 0);
            sI1 = __builtin_amdgcn_mfma_f32_16x16x32_bf16(aR1, bEi_b,  sI1, 0, 0, 0);
            sI1 = __builtin_amdgcn_mfma_f32_16x16x32_bf16(aI1, bEr_b,  sI1, 0, 0, 0);
            {
                const float2 e = eyT[y0][16 + kl];
#pragma unroll
                for (int r = 0; r < 4; ++r) {
                    cR0b[r] += e.x * sR0[r] - e.y * sI0[r];
                    cI0b[r] += e.x * sI0[r] + e.y * sR0[r];
                    cR1b[r] += e.x * sR1[r] - e.y * sI1[r];
                    cI1b[r] += e.x * sI1[r] + e.y * sR1[r];
                }
            }
        }

        // ======== y = y0+1 (rows +32): kg=a then kg=b ========
        {
            const bf16x8 aR0 = *(const bf16x8*)&aLds[0][32 + kl][xw];
            const bf16x8 aI0 = *(const bf16x8*)&aLds[1][32 + kl][xw];
            const bf16x8 aR1 = *(const bf16x8*)&aLds[0][32 + kl + 16][xw];
            const bf16x8 aI1 = *(const bf16x8*)&aLds[1][32 + kl + 16][xw];

            f32x4 rR0 = {0.f,0.f,0.f,0.f}, rI0 = {0.f,0.f,0.f,0.f};
            f32x4 rR1 = {0.f,0.f,0.f,0.f}, rI1 = {0.f,0.f,0.f,0.f};
            rR0 = __builtin_amdgcn_mfma_f32_16x16x32_bf16(aR0, bEr_a,  rR0, 0, 0, 0);
            rR0 = __builtin_amdgcn_mfma_f32_16x16x32_bf16(aI0, bEiN_a, rR0, 0, 0, 0);
            rI0 = __builtin_amdgcn_mfma_f32_16x16x32_bf16(aR0, bEi_a,  rI0, 0, 0, 0);
            rI0 = __builtin_amdgcn_mfma_f32_16x16x32_bf16(aI0, bEr_a,  rI0, 0, 0, 0);
            rR1 = __builtin_amdgcn_mfma_f32_16x16x32_bf16(aR1, bEr_a,  rR1, 0, 0, 0);
            rR1 = __builtin_amdgcn_mfma_f32_16x16x32_bf16(aI1, bEiN_a, rR1, 0, 0, 0);
            rI1 = __builtin_amdgcn_mfma_f32_16x16x32_bf16(aR1, bEi_a,  rI1, 0, 0, 0);
            rI1 = __builtin_amdgcn_mfma_f32_16x16x32_bf16(aI1, bEr_a,  rI1, 0, 0, 0);
            {
                const float2 e = eyT[y0 + 1][kl];
#pragma unroll
                for (int r = 0; r < 4; ++r) {
                    cR0a[r] += e.x * rR0[r] - e.y * rI0[r];
                    cI0a[r] += e.x * rI0[r] + e.y * rR0[r];
                    cR1a[r] += e.x * rR1[r] - e.y * rI1[r];
                    cI1a[r] += e.x * rI1[r] + e.y * rR1[r];
                }
            }

            f32x4 sR0 = {0.f,0.f,0.f,0.f}, sI0 = {0.f,0.f,0.f,0.f};
            f32x4 sR1 = {0.f,0.f,0.f,0.f}, sI1 = {0.f,0.f,0.f,0.f};
            sR0 = __builtin_amdgcn_mfma_f32_16x16x32_bf16(aR0, bEr_b,  sR0, 0, 0, 0);
            sR0 = __builtin_amdgcn_mfma_f32_16x16x32_bf16(aI0, bEiN_b, sR0, 0, 0, 0);
            sI0 = __builtin_amdgcn_mfma_f32_16x16x32_bf16(aR0, bEi_b,  sI0, 0, 0, 0);
            sI0 = __builtin_amdgcn_mfma_f32_16x16x32_bf16(aI0, bEr_b,  sI0, 0, 0, 0);
            sR1 = __builtin_amdgcn_mfma_f32_16x16x32_bf16(aR1, bEr_b,  sR1, 0, 0, 0);
            sR1 = __builtin_amdgcn_mfma_f32_16x16x32_bf16(aI1, bEiN_b, sR1, 0, 0, 0);
            sI1 = __builtin_amdgcn_mfma_f32_16x16x32_bf16(aR1, bEi_b,  sI1, 0, 0, 0);
            sI1 = __builtin_amdgcn_mfma_f32_16x16x32_bf16(aI1, bEr_b,  sI1, 0, 0, 0);
            {
                const float2 e = eyT[y0 + 1][16 + kl];
#pragma unroll
                for (int r = 0; r < 4; ++r) {
                    cR0b[r] += e.x * sR0[r] - e.y * sI0[r];
                    cI0b[r] += e.x * sI0[r] + e.y * sR0[r];
                    cR1b[r] += e.x * sR1[r] - e.y * sI1[r];
                    cI1b[r] += e.x * sI1[r] + e.y * sR1[r];
                }
            }
        }
        __syncthreads();   // protect aLds before next stage
    }

    // ---- cross-wave reduction (R22 pattern, widened to 2 kg) ----
    const int slot = wv & 1;
    if (wv < 2) {
#pragma unroll
        for (int r = 0; r < 4; ++r) {
            const int nn  = g * 4 + r;
            const int i00 = (nn * 16 + kl) * 2;
            const int i10 = ((nn + 16) * 16 + kl) * 2;
            red[slot][i00]            = cR0a[r];
            red[slot][i00 + 1]        = cI0a[r];
            red[slot][i10]            = cR1a[r];
            red[slot][i10 + 1]        = cI1a[r];
            red[slot][1024 + i00]     = cR0b[r];
            red[slot][1024 + i00 + 1] = cI0b[r];
            red[slot][1024 + i10]     = cR1b[r];
            red[slot][1024 + i10 + 1] = cI1b[r];
        }
    }
    __syncthreads();
    if (wv >= 2) {
#pragma unroll
        for (int r = 0; r < 4; ++r) {
            const int nn  = g * 4 + r;
            const int i00 = (nn * 16 + kl) * 2;
            const int i10 = ((nn + 16) * 16 + kl) * 2;
            red[slot][i00]            += cR0a[r];
            red[slot][i00 + 1]        += cI0a[r];
            red[slot][i10]            += cR1a[r];
            red[slot][i10 + 1]        += cI1a[r];
            red[slot][1024 + i00]     += cR0b[r];
            red[slot][1024 + i00 + 1] += cI0b[r];
            red[slot][1024 + i10]     += cR1b[r];
            red[slot][1024 + i10 + 1] += cI1b[r];
        }
    }
    __syncthreads();

    {
        const int bp = ((t * 64 + ktp) * 4 + yq) * 2048;
        for (int f = tid; f < 2048; f += NTHR)
            part[bp + f] = red[0][f] + red[1][f];
    }
}

// ---------------------------------------------------------------------------
// Kernel 3: sum 4 y-quarter partials, f32 planar output (R17-R23 + kg bit).
// ---------------------------------------------------------------------------
__global__ __launch_bounds__(256)
void reduce_out(const float* __restrict__ part, float* __restrict__ out)
{
    const int gidx = blockIdx.x * 256 + threadIdx.x;  // [0, 131072)
    const int t   = gidx >> 16;
    const int r1  = gidx & 65535;
    const int ktp = r1 >> 10;
    const int r2  = r1 & 1023;
    const int kg  = r2 >> 9;
    const int r3  = r2 & 511;
    const int n   = r3 >> 4;
    const int kl  = r3 & 15;

    const int base = ((t * 64 + ktp) * 4) * 2048;
    const int fr   = kg * 1024 + (n * 16 + kl) * 2;
    float re = 0.f, im = 0.f;
#pragma unroll
    for (int yqi = 0; yqi < 4; ++yqi) {
        re += part[base + yqi * 2048 + fr];
        im += part[base + yqi * 2048 + fr + 1];
    }

    const int k  = ktp * 32 + kg * 16 + kl;
    const int oi = (t * 32 + n) * 2048 + k;
    out[oi]           = re;    // real plane
    out[131072 + oi]  = im;    // imag plane
}

extern "C" void kernel_launch(void* const* d_in, const int* in_sizes, int n_in,
                              void* d_out, int out_size, void* d_ws, size_t ws_size,
                              hipStream_t stream) {
    const float* imr  = (const float*)d_in[0];
    const float* imi  = (const float*)d_in[1];
    const float* csr  = (const float*)d_in[2];
    const float* csi  = (const float*)d_in[3];
    const float* traj = (const float*)d_in[4];
    float* out = (float*)d_out;

    unsigned short* mRb = (unsigned short*)d_ws;
    unsigned short* mIb = mRb + MULTI_ELEMS;
    float* part = (float*)((char*)d_ws + PART_OFF);

    make_multi_bf16<<<dim3(1024), dim3(256), 0, stream>>>(imr, imi, csr, csi, mRb, mIb);
    nufft_mfma12<<<dim3(512), dim3(NTHR), 0, stream>>>(traj, mRb, mIb, part);
    reduce_out<<<dim3(512), dim3(256), 0, stream>>>(part, out);
}

// Round 26
// 48.389 us; speedup vs baseline: 1.6788x; 1.0010x over previous
//
#include <hip/hip_runtime.h>
#include <math.h>

typedef __attribute__((ext_vector_type(8))) short bf16x8;
typedef __attribute__((ext_vector_type(4))) float f32x4;

#define NK   2048
#define NTHR 256   // 4 waves

// ws: mRb bf16[1M] @0 (2MB), mIb @2MB (2MB), part f32[2*64*4*2048] @4MB (4MB)
#define MULTI_ELEMS (1 << 20)
#define PART_OFF    (4u << 20)

__device__ __forceinline__ unsigned short f2bf(float f) {
    union { float f; unsigned u; } v; v.f = f;
    const unsigned r = (v.u + 0x7fffu + ((v.u >> 16) & 1u)) >> 16;  // RNE
    return (unsigned short)r;
}

// ---------------------------------------------------------------------------
// Kernel 1: multi = image*csm -> bf16 planes (proven R12-R24, verbatim)
// ---------------------------------------------------------------------------
__global__ __launch_bounds__(256)
void make_multi_bf16(const float* __restrict__ imr, const float* __restrict__ imi,
                     const float* __restrict__ csr, const float* __restrict__ csi,
                     unsigned short* __restrict__ mRb, unsigned short* __restrict__ mIb)
{
    const int gid = blockIdx.x * 256 + threadIdx.x;
    const int p   = gid * 4;
    const int x   = p & 127;
    const int y   = (p >> 7) & 127;
    const int n   = (p >> 14) & 31;
    const int t   = p >> 19;
    const int d   = n & 3;
    const int ch  = n >> 2;
    const int io  = ((t * 4 + d) * 128 + y) * 128 + x;
    const int co  = (((t * 8 + ch) * 4 + d) * 128 + y) * 128 + x;

    const float4 ar = *(const float4*)(imr + io);
    const float4 ai = *(const float4*)(imi + io);
    const float4 br = *(const float4*)(csr + co);
    const float4 bi = *(const float4*)(csi + co);

    ushort4 sr, si;
    sr.x = f2bf(ar.x*br.x - ai.x*bi.x);  si.x = f2bf(ar.x*bi.x + ai.x*br.x);
    sr.y = f2bf(ar.y*br.y - ai.y*bi.y);  si.y = f2bf(ar.y*bi.y + ai.y*br.y);
    sr.z = f2bf(ar.z*br.z - ai.z*bi.z);  si.z = f2bf(ar.z*bi.z + ai.z*br.z);
    sr.w = f2bf(ar.w*br.w - ai.w*bi.w);  si.w = f2bf(ar.w*bi.w + ai.w*br.w);
    *(ushort4*)(mRb + p) = sr;
    *(ushort4*)(mIb + p) = si;
}

// ---------------------------------------------------------------------------
// Kernel 2: R23 structure; each block computes TWO kt (32 k) from the same
// staged tile. Grid 512 = 2t x 64 ktp x 4 yq. All patterns proven:
// table loop (constants widened to 32 k), named-reg B/acc duplication (R22
// mold), transient exT + red aliasing in aLds region (R23 mold).
// Lane maps HW-proven R13-R23: A row=kl(/+16); B col=kl; C row=g*4+r, col=kl.
// LDS: eyT[128][32] (32KB) | region{ exT[128][32] (32KB) -> aLds[2][64][136]
// (34.8KB) -> red[2][2048] (16KB) }, barrier-separated. 67.6KB -> 2 blk/CU.
// ---------------------------------------------------------------------------
__global__ __launch_bounds__(NTHR, 2)
void nufft_mfma12(const float* __restrict__ traj,
                  const unsigned short* __restrict__ mRb,
                  const unsigned short* __restrict__ mIb,
                  float* __restrict__ part)
{
    __shared__ __align__(16) unsigned char sm[32768 + 2 * 64 * 136 * 2];  // 67584 B
    float2 (*eyT)[32] = reinterpret_cast<float2 (*)[32]>(sm);                     // [128][32]
    float2 (*exT)[32] = reinterpret_cast<float2 (*)[32]>(sm + 32768);             // [128][32] transient
    unsigned short (*aLds)[64][136] =
        reinterpret_cast<unsigned short (*)[64][136]>(sm + 32768);                // [2][64][136]
    float (*red)[2048] = reinterpret_cast<float (*)[2048]>(sm + 32768);           // [2][2048] post-loop

    const int b   = blockIdx.x;          // [0, 512)
    const int xcd = b & 7;               // XCD swizzle: 0-3 -> t=0, 4-7 -> t=1
    const int t   = xcd >> 2;
    const int idx = (xcd & 3) * 64 + (b >> 3);   // bijective [0,256)
    const int ktp = idx >> 2;            // kt-pair [0,64)
    const int yq  = idx & 3;             // y-quarter
    const int k0  = ktp * 32;
    const int tid = threadIdx.x;

    // ---- tables: exp(-i * kv * (c-64)) for 32 k (R23 loop, widened) ----
    for (int i = tid; i < 2 * 128 * 32; i += NTHR) {
        const int ax  = i >> 12;         // 0=y (ky), 1=x (kx)
        const int rem = i & 4095;
        const int c   = rem >> 5;
        const int kli = rem & 31;
        const float kv = traj[(t * 2 + ax) * NK + k0 + kli];
        float s, co;
        sincosf(-kv * (float)(c - 64), &s, &co);
        if (ax == 0) eyT[c][kli] = make_float2(co, s);
        else         exT[c][kli] = make_float2(co, s);
    }
    __syncthreads();

    const int wv = tid >> 6;             // 0..3 = this wave's x-slice
    const int l  = tid & 63;
    const int kl = l & 15;
    const int g  = l >> 4;
    const int xw = wv * 32 + g * 8;      // lane's x-offset in the y-row

    // ---- B frags for kg=0 (k0+kl) and kg=1 (k0+16+kl), named regs ----
    bf16x8 bEr_a, bEiN_a, bEi_a, bEr_b, bEiN_b, bEi_b;
#pragma unroll
    for (int j = 0; j < 8; ++j) {
        const float2 exa = exT[xw + j][kl];
        bEr_a[j]  = (short)f2bf(exa.x);
        bEiN_a[j] = (short)f2bf(-exa.y);
        bEi_a[j]  = (short)(bEiN_a[j] ^ (short)0x8000);
        const float2 exb = exT[xw + j][16 + kl];
        bEr_b[j]  = (short)f2bf(exb.x);
        bEiN_b[j] = (short)f2bf(-exb.y);
        bEi_b[j]  = (short)(bEiN_b[j] ^ (short)0x8000);
    }
    __syncthreads();   // all waves done reading exT before staging overwrites it

    f32x4 cR0a = {0.f,0.f,0.f,0.f}, cI0a = {0.f,0.f,0.f,0.f};
    f32x4 cR1a = {0.f,0.f,0.f,0.f}, cI1a = {0.f,0.f,0.f,0.f};
    f32x4 cR0b = {0.f,0.f,0.f,0.f}, cI0b = {0.f,0.f,0.f,0.f};
    f32x4 cR1b = {0.f,0.f,0.f,0.f}, cI1b = {0.f,0.f,0.f,0.f};

    for (int pp = 0; pp < 16; ++pp) {
        const int y0 = yq * 32 + pp * 2;

        // ---- stage TWO y-rows (R22/R23 verbatim) ----
#pragma unroll
        for (int q = 0; q < 4; ++q) {
            const int s  = (q * 256 + tid) * 8;   // [0, 8192), step 8
            const int nr = s >> 7;                // 0..63
            const int x  = s & 127;
            const int n  = nr & 31;
            const int yy = nr >> 5;
            const size_t go = (((size_t)(t * 32 + n)) << 14) + (y0 + yy) * 128 + x;
            *(bf16x8*)&aLds[0][nr][x] = *(const bf16x8*)(mRb + go);
            *(bf16x8*)&aLds[1][nr][x] = *(const bf16x8*)(mIb + go);
        }
        __syncthreads();

        // ======== y = y0 (rows +0): kg=a then kg=b — R22 mold ========
        {
            const bf16x8 aR0 = *(const bf16x8*)&aLds[0][kl][xw];
            const bf16x8 aI0 = *(const bf16x8*)&aLds[1][kl][xw];
            const bf16x8 aR1 = *(const bf16x8*)&aLds[0][kl + 16][xw];
            const bf16x8 aI1 = *(const bf16x8*)&aLds[1][kl + 16][xw];

            f32x4 rR0 = {0.f,0.f,0.f,0.f}, rI0 = {0.f,0.f,0.f,0.f};
            f32x4 rR1 = {0.f,0.f,0.f,0.f}, rI1 = {0.f,0.f,0.f,0.f};
            rR0 = __builtin_amdgcn_mfma_f32_16x16x32_bf16(aR0, bEr_a,  rR0, 0, 0, 0);
            rR0 = __builtin_amdgcn_mfma_f32_16x16x32_bf16(aI0, bEiN_a, rR0, 0, 0, 0);
            rI0 = __builtin_amdgcn_mfma_f32_16x16x32_bf16(aR0, bEi_a,  rI0, 0, 0, 0);
            rI0 = __builtin_amdgcn_mfma_f32_16x16x32_bf16(aI0, bEr_a,  rI0, 0, 0, 0);
            rR1 = __builtin_amdgcn_mfma_f32_16x16x32_bf16(aR1, bEr_a,  rR1, 0, 0, 0);
            rR1 = __builtin_amdgcn_mfma_f32_16x16x32_bf16(aI1, bEiN_a, rR1, 0, 0, 0);
            rI1 = __builtin_amdgcn_mfma_f32_16x16x32_bf16(aR1, bEi_a,  rI1, 0, 0, 0);
            rI1 = __builtin_amdgcn_mfma_f32_16x16x32_bf16(aI1, bEr_a,  rI1, 0, 0, 0);
            {
                const float2 e = eyT[y0][kl];
#pragma unroll
                for (int r = 0; r < 4; ++r) {
                    cR0a[r] += e.x * rR0[r] - e.y * rI0[r];
                    cI0a[r] += e.x * rI0[r] + e.y * rR0[r];
                    cR1a[r] += e.x * rR1[r] - e.y * rI1[r];
                    cI1a[r] += e.x * rI1[r] + e.y * rR1[r];
                }
            }

            f32x4 sR0 = {0.f,0.f,0.f,0.f}, sI0 = {0.f,0.f,0.f,0.f};
            f32x4 sR1 = {0.f,0.f,0.f,0.f}, sI1 = {0.f,0.f,0.f,0.f};
            sR0 = __builtin_amdgcn_mfma_f32_16x16x32_bf16(aR0, bEr_b,  sR0, 0, 0, 0);
            sR0 = __builtin_amdgcn_mfma_f32_16x16x32_bf16(aI0, bEiN_b, sR0, 0, 0, 0);
            sI0 = __builtin_amdgcn_mfma_f32_16x16x32_bf16(aR0, bEi_b,  sI0, 0, 0, 0);
            sI0 = __builtin_amdgcn_mfma_f32_16x16x32_bf16(aI0, bEr_b,  sI0, 0, 0, 0);
            sR1 = __builtin_amdgcn_mfma_f32_16x16x32_bf16(aR1, bEr_b,  sR1, 0, 0, 0);
            sR1 = __builtin_amdgcn_mfma_f32_16x16x32_bf16(aI1, bEiN_b, sR1, 0, 0, 0);
            sI1 = __builtin_amdgcn_mfma_f32_16x16x32_bf16(aR1, bEi_b,  sI1, 0, 0, 0);
            sI1 = __builtin_amdgcn_mfma_f32_16x16x32_bf16(aI1, bEr_b,  sI1, 0, 0, 0);
            {
                const float2 e = eyT[y0][16 + kl];
#pragma unroll
                for (int r = 0; r < 4; ++r) {
                    cR0b[r] += e.x * sR0[r] - e.y * sI0[r];
                    cI0b[r] += e.x * sI0[r] + e.y * sR0[r];
                    cR1b[r] += e.x * sR1[r] - e.y * sI1[r];
                    cI1b[r] += e.x * sI1[r] + e.y * sR1[r];
                }
            }
        }

        // ======== y = y0+1 (rows +32): kg=a then kg=b ========
        {
            const bf16x8 aR0 = *(const bf16x8*)&aLds[0][32 + kl][xw];
            const bf16x8 aI0 = *(const bf16x8*)&aLds[1][32 + kl][xw];
            const bf16x8 aR1 = *(const bf16x8*)&aLds[0][32 + kl + 16][xw];
            const bf16x8 aI1 = *(const bf16x8*)&aLds[1][32 + kl + 16][xw];

            f32x4 rR0 = {0.f,0.f,0.f,0.f}, rI0 = {0.f,0.f,0.f,0.f};
            f32x4 rR1 = {0.f,0.f,0.f,0.f}, rI1 = {0.f,0.f,0.f,0.f};
            rR0 = __builtin_amdgcn_mfma_f32_16x16x32_bf16(aR0, bEr_a,  rR0, 0, 0, 0);
            rR0 = __builtin_amdgcn_mfma_f32_16x16x32_bf16(aI0, bEiN_a, rR0, 0, 0, 0);
            rI0 = __builtin_amdgcn_mfma_f32_16x16x32_bf16(aR0, bEi_a,  rI0, 0, 0, 0);
            rI0 = __builtin_amdgcn_mfma_f32_16x16x32_bf16(aI0, bEr_a,  rI0, 0, 0, 0);
            rR1 = __builtin_amdgcn_mfma_f32_16x16x32_bf16(aR1, bEr_a,  rR1, 0, 0, 0);
            rR1 = __builtin_amdgcn_mfma_f32_16x16x32_bf16(aI1, bEiN_a, rR1, 0, 0, 0);
            rI1 = __builtin_amdgcn_mfma_f32_16x16x32_bf16(aR1, bEi_a,  rI1, 0, 0, 0);
            rI1 = __builtin_amdgcn_mfma_f32_16x16x32_bf16(aI1, bEr_a,  rI1, 0, 0, 0);
            {
                const float2 e = eyT[y0 + 1][kl];
#pragma unroll
                for (int r = 0; r < 4; ++r) {
                    cR0a[r] += e.x * rR0[r] - e.y * rI0[r];
                    cI0a[r] += e.x * rI0[r] + e.y * rR0[r];
                    cR1a[r] += e.x * rR1[r] - e.y * rI1[r];
                    cI1a[r] += e.x * rI1[r] + e.y * rR1[r];
                }
            }

            f32x4 sR0 = {0.f,0.f,0.f,0.f}, sI0 = {0.f,0.f,0.f,0.f};
            f32x4 sR1 = {0.f,0.f,0.f,0.f}, sI1 = {0.f,0.f,0.f,0.f};
            sR0 = __builtin_amdgcn_mfma_f32_16x16x32_bf16(aR0, bEr_b,  sR0, 0, 0, 0);
            sR0 = __builtin_amdgcn_mfma_f32_16x16x32_bf16(aI0, bEiN_b, sR0, 0, 0, 0);
            sI0 = __builtin_amdgcn_mfma_f32_16x16x32_bf16(aR0, bEi_b,  sI0, 0, 0, 0);
            sI0 = __builtin_amdgcn_mfma_f32_16x16x32_bf16(aI0, bEr_b,  sI0, 0, 0, 0);
            sR1 = __builtin_amdgcn_mfma_f32_16x16x32_bf16(aR1, bEr_b,  sR1, 0, 0, 0);
            sR1 = __builtin_amdgcn_mfma_f32_16x16x32_bf16(aI1, bEiN_b, sR1, 0, 0, 0);
            sI1 = __builtin_amdgcn_mfma_f32_16x16x32_bf16(aR1, bEi_b,  sI1, 0, 0, 0);
            sI1 = __builtin_amdgcn_mfma_f32_16x16x32_bf16(aI1, bEr_b,  sI1, 0, 0, 0);
            {
                const float2 e = eyT[y0 + 1][16 + kl];
#pragma unroll
                for (int r = 0; r < 4; ++r) {
                    cR0b[r] += e.x * sR0[r] - e.y * sI0[r];
                    cI0b[r] += e.x * sI0[r] + e.y * sR0[r];
                    cR1b[r] += e.x * sR1[r] - e.y * sI1[r];
                    cI1b[r] += e.x * sI1[r] + e.y * sR1[r];
                }
            }
        }
        __syncthreads();   // protect aLds before next stage
    }

    // ---- cross-wave reduction (R22 pattern, widened to 2 kg) ----
    const int slot = wv & 1;
    if (wv < 2) {
#pragma unroll
        for (int r = 0; r < 4; ++r) {
            const int nn  = g * 4 + r;
            const int i00 = (nn * 16 + kl) * 2;
            const int i10 = ((nn + 16) * 16 + kl) * 2;
            red[slot][i00]            = cR0a[r];
            red[slot][i00 + 1]        = cI0a[r];
            red[slot][i10]            = cR1a[r];
            red[slot][i10 + 1]        = cI1a[r];
            red[slot][1024 + i00]     = cR0b[r];
            red[slot][1024 + i00 + 1] = cI0b[r];
            red[slot][1024 + i10]     = cR1b[r];
            red[slot][1024 + i10 + 1] = cI1b[r];
        }
    }
    __syncthreads();
    if (wv >= 2) {
#pragma unroll
        for (int r = 0; r < 4; ++r) {
            const int nn  = g * 4 + r;
            const int i00 = (nn * 16 + kl) * 2;
            const int i10 = ((nn + 16) * 16 + kl) * 2;
            red[slot][i00]            += cR0a[r];
            red[slot][i00 + 1]        += cI0a[r];
            red[slot][i10]            += cR1a[r];
            red[slot][i10 + 1]        += cI1a[r];
            red[slot][1024 + i00]     += cR0b[r];
            red[slot][1024 + i00 + 1] += cI0b[r];
            red[slot][1024 + i10]     += cR1b[r];
            red[slot][1024 + i10 + 1] += cI1b[r];
        }
    }
    __syncthreads();

    {
        const int bp = ((t * 64 + ktp) * 4 + yq) * 2048;
        for (int f = tid; f < 2048; f += NTHR)
            part[bp + f] = red[0][f] + red[1][f];
    }
}

// ---------------------------------------------------------------------------
// Kernel 3: sum 4 y-quarter partials, f32 planar output (R17-R23 + kg bit).
// ---------------------------------------------------------------------------
__global__ __launch_bounds__(256)
void reduce_out(const float* __restrict__ part, float* __restrict__ out)
{
    const int gidx = blockIdx.x * 256 + threadIdx.x;  // [0, 131072)
    const int t   = gidx >> 16;
    const int r1  = gidx & 65535;
    const int ktp = r1 >> 10;
    const int r2  = r1 & 1023;
    const int kg  = r2 >> 9;
    const int r3  = r2 & 511;
    const int n   = r3 >> 4;
    const int kl  = r3 & 15;

    const int base = ((t * 64 + ktp) * 4) * 2048;
    const int fr   = kg * 1024 + (n * 16 + kl) * 2;
    float re = 0.f, im = 0.f;
#pragma unroll
    for (int yqi = 0; yqi < 4; ++yqi) {
        re += part[base + yqi * 2048 + fr];
        im += part[base + yqi * 2048 + fr + 1];
    }

    const int k  = ktp * 32 + kg * 16 + kl;
    const int oi = (t * 32 + n) * 2048 + k;
    out[oi]           = re;    // real plane
    out[131072 + oi]  = im;    // imag plane
}

extern "C" void kernel_launch(void* const* d_in, const int* in_sizes, int n_in,
                              void* d_out, int out_size, void* d_ws, size_t ws_size,
                              hipStream_t stream) {
    const float* imr  = (const float*)d_in[0];
    const float* imi  = (const float*)d_in[1];
    const float* csr  = (const float*)d_in[2];
    const float* csi  = (const float*)d_in[3];
    const float* traj = (const float*)d_in[4];
    float* out = (float*)d_out;

    unsigned short* mRb = (unsigned short*)d_ws;
    unsigned short* mIb = mRb + MULTI_ELEMS;
    float* part = (float*)((char*)d_ws + PART_OFF);

    make_multi_bf16<<<dim3(1024), dim3(256), 0, stream>>>(imr, imi, csr, csi, mRb, mIb);
    nufft_mfma12<<<dim3(512), dim3(NTHR), 0, stream>>>(traj, mRb, mIb, part);
    reduce_out<<<dim3(512), dim3(256), 0, stream>>>(part, out);
}